// Round 5
// baseline (60314.996 us; speedup 1.0000x reference)
//
#include <hip/hip_runtime.h>
#include <math.h>

#define BB   64
#define TENC 128
#define TDEC 64
#define DHH  1024
#define DVV  2048
#define NCHN 256
#define GG   8704   // 4*DV + 2*NCH
#define KTOT 3072   // DH + DV

typedef unsigned short u16;
typedef __bf16 bf16x8 __attribute__((ext_vector_type(8)));
typedef float  f32x4  __attribute__((ext_vector_type(4)));

__device__ __forceinline__ u16 f2bf(float f) {
    unsigned u = __float_as_uint(f);
    unsigned r = (u + 0x7fffu + ((u >> 16) & 1u)) >> 16;
    return (u16)r;
}
__device__ __forceinline__ float bf2f(u16 s) { return __uint_as_float(((unsigned)s) << 16); }
__device__ __forceinline__ float tanh_fast(float x) {
    float xc = fminf(fmaxf(x, -15.f), 15.f);
    float t = __expf(2.f * xc);
    return 1.f - 2.f * __builtin_amdgcn_rcpf(t + 1.f);
}
__device__ __forceinline__ float sigmoid_fast(float x) {
    float xc = fminf(fmaxf(x, -30.f), 30.f);
    return __builtin_amdgcn_rcpf(1.f + __expf(-xc));
}

// ---- contention-free grid barrier ----
// flags[blk*32]: per-block arrival (own cacheline, release store).
// block 0 wave 0 polls all flags with device-scope LOADS, then publishes gen.
// Other blocks spin on gen with device-scope loads. No RMW in any spin path.
__device__ __forceinline__ void gbar(int* flags, int* gen, int target) {
    __syncthreads();
    __threadfence();     // make this block's data visible device-wide
    int tid = threadIdx.x;
    if (tid == 0)
        __hip_atomic_store(flags + blockIdx.x * 32, target,
                           __ATOMIC_RELEASE, __HIP_MEMORY_SCOPE_AGENT);
    if (blockIdx.x == 0) {
        if (tid < 64) {
#pragma unroll
            for (int i = 0; i < 4; ++i) {
                int idx = (tid * 4 + i) * 32;
                while (__hip_atomic_load(flags + idx, __ATOMIC_ACQUIRE,
                                         __HIP_MEMORY_SCOPE_AGENT) < target)
                    __builtin_amdgcn_s_sleep(1);
            }
        }
        __syncthreads();
        if (tid == 0)
            __hip_atomic_store(gen, target, __ATOMIC_RELEASE, __HIP_MEMORY_SCOPE_AGENT);
    } else {
        if (tid == 0) {
            while (__hip_atomic_load(gen, __ATOMIC_ACQUIRE,
                                     __HIP_MEMORY_SCOPE_AGENT) < target)
                __builtin_amdgcn_s_sleep(1);
        }
        __syncthreads();
    }
    __threadfence();     // see other blocks' data
}

// ===================== precompute kernels =====================

__global__ __launch_bounds__(256) void k_init2(float* c, u16* xh, u16* xl, int* bar) {
    int i = blockIdx.x * 256 + threadIdx.x;   // grid 768 -> 196608
    xh[i] = 0; xl[i] = 0;
    if (i < BB * DVV) c[i] = 0.f;
    if (i < 8448) bar[i] = 0;
}

// transpose+convert: D[n][k] = bf16(S[k][n]) (hi, optionally lo residual)
template <bool LO>
__global__ __launch_bounds__(256) void k_cvt(const float* __restrict__ S1,
                                             const float* __restrict__ S2,
                                             int K1, int N, int K,
                                             u16* __restrict__ Dh,
                                             u16* __restrict__ Dl) {
    __shared__ float t[64][65];
    int n0 = blockIdx.x * 64, k0 = blockIdx.y * 64;
    int tid = threadIdx.x;
    int cn = tid & 63, r4 = tid >> 6;
#pragma unroll
    for (int p = 0; p < 16; ++p) {
        int kk = p * 4 + r4;
        int kg = k0 + kk;
        const float* src = (kg < K1) ? S1 + (size_t)kg * N : S2 + (size_t)(kg - K1) * N;
        t[kk][cn] = src[n0 + cn];
    }
    __syncthreads();
    int ck = tid & 63, n4 = tid >> 6;
#pragma unroll
    for (int p = 0; p < 16; ++p) {
        int nn = p * 4 + n4;
        float w = t[ck][nn];
        u16 hi = f2bf(w);
        size_t o = (size_t)(n0 + nn) * K + k0 + ck;
        Dh[o] = hi;
        if (LO) Dl[o] = f2bf(w - bf2f(hi));
    }
}

// P = enc @ W1[:DH] + b1, f32 SMEM GEMM, bf16 store
__global__ __launch_bounds__(256) void k_Pb(const float* __restrict__ enc,
                                            const float* __restrict__ W1,
                                            const float* __restrict__ b1,
                                            u16* __restrict__ Pb) {
    __shared__ float As[32][68];
    __shared__ float Bs[32][68];
    int j0 = blockIdx.x * 64;
    int m0 = blockIdx.y * 64;
    int tid = threadIdx.x;
    int jg = tid & 15, bg = tid >> 4;
    float acc[4][4] = {};
    for (int k0 = 0; k0 < DHH; k0 += 32) {
#pragma unroll
        for (int p = 0; p < 8; ++p) {
            int r = p * 8 + (tid >> 5);
            int kk = tid & 31;
            As[kk][r] = enc[(size_t)(m0 + r) * DHH + k0 + kk];
        }
#pragma unroll
        for (int p = 0; p < 8; ++p) {
            int kk = p * 4 + (tid >> 6);
            int jl = tid & 63;
            Bs[kk][jl] = W1[(size_t)(k0 + kk) * DHH + j0 + jl];
        }
        __syncthreads();
#pragma unroll
        for (int kk = 0; kk < 32; ++kk) {
            float4 a = *(const float4*)&As[kk][bg * 4];
            float4 b = *(const float4*)&Bs[kk][jg * 4];
            float av[4] = {a.x, a.y, a.z, a.w};
            float bv[4] = {b.x, b.y, b.z, b.w};
#pragma unroll
            for (int i = 0; i < 4; ++i)
#pragma unroll
                for (int j = 0; j < 4; ++j) acc[i][j] += av[i] * bv[j];
        }
        __syncthreads();
    }
    float4 bb = *(const float4*)&b1[j0 + jg * 4];
    float bia[4] = {bb.x, bb.y, bb.z, bb.w};
#pragma unroll
    for (int i = 0; i < 4; ++i) {
        int r = m0 + bg * 4 + i;
        ushort4 sv;
        sv.x = f2bf(acc[i][0] + bia[0]);
        sv.y = f2bf(acc[i][1] + bia[1]);
        sv.z = f2bf(acc[i][2] + bia[2]);
        sv.w = f2bf(acc[i][3] + bia[3]);
        *(ushort4*)&Pb[(size_t)r * DHH + j0 + jg * 4] = sv;
    }
}

// ===================== persistent decode kernel =====================

__global__ __launch_bounds__(512) void k_decode(
        const u16* Pbf, float* hWp, float* ebuf, float* gp, float* c,
        u16* xh, u16* xl,
        const u16* __restrict__ Wth, const u16* __restrict__ Wtl,
        const u16* __restrict__ Wta,
        const float* __restrict__ enc, const float* __restrict__ w2,
        const float* __restrict__ bih, const float* __restrict__ bhh,
        float* out, int* bar) {
    __shared__ float smem[4352];   // 17.4 KB, reused per phase
    int* flags = bar;
    int* gen = bar + 8192;
    int blk = blockIdx.x, tid = threadIdx.x;
    int wv = tid >> 6, l = tid & 63;
    int lr = l & 15, lk4 = l >> 4;
    f32x4 z = {0.f, 0.f, 0.f, 0.f};
    int bt = 1;

    for (int t = 0; t < TDEC; ++t) {
        // ---------- phase A: hW partials (16 n-tiles x 16 ksegs of 128) ----------
        {
            int nt = blk & 15, kseg = blk >> 4;
            int wn = wv & 3, kh = wv >> 2;
            int n = nt * 64 + wn * 16 + lr;
            int kb = kseg * 128 + kh * 64;
            const u16* wp = Wta + (size_t)n * 2048 + kb + lk4 * 8;
            const u16* ap = xh + (size_t)lr * KTOT + 1024 + kb + lk4 * 8;
            f32x4 acc[4] = {z, z, z, z};
#pragma unroll
            for (int kk = 0; kk < 64; kk += 32) {
                bf16x8 bfrag = *(const bf16x8*)(wp + kk);
#pragma unroll
                for (int mf = 0; mf < 4; ++mf) {
                    bf16x8 a = *(const bf16x8*)(ap + (size_t)mf * 16 * KTOT + kk);
                    acc[mf] = __builtin_amdgcn_mfma_f32_16x16x32_bf16(a, bfrag, acc[mf], 0, 0, 0);
                }
            }
            float* red = smem;   // 64 x 68
            if (kh == 0) {
#pragma unroll
                for (int mf = 0; mf < 4; ++mf)
#pragma unroll
                    for (int r = 0; r < 4; ++r)
                        red[(mf * 16 + lk4 * 4 + r) * 68 + wn * 16 + lr] = acc[mf][r];
            }
            __syncthreads();
            if (kh == 1) {
#pragma unroll
                for (int mf = 0; mf < 4; ++mf)
#pragma unroll
                    for (int r = 0; r < 4; ++r) {
                        int m = mf * 16 + lk4 * 4 + r;
                        hWp[(size_t)(kseg * 64 + m) * DHH + n] =
                            acc[mf][r] + red[m * 68 + wn * 16 + lr];
                    }
            }
        }
        gbar(flags, gen, bt++);

        // ---------- phase B: e[b,t] (blocks = (b, tgroup of 32 t)) ----------
        {
            int b = blk >> 2, tg = blk & 3;
            float* hw = smem;          // 1024
            float* w2s = smem + 1024;  // 1024
#pragma unroll
            for (int p = 0; p < 2; ++p) {
                int d = p * 512 + tid;
                float s = 0.f;
#pragma unroll
                for (int ks = 0; ks < 16; ++ks) s += hWp[(size_t)(ks * 64 + b) * DHH + d];
                hw[d] = s;
                w2s[d] = w2[d];
            }
            __syncthreads();
            const u16* Pb = Pbf + (size_t)b * TENC * DHH;
#pragma unroll
            for (int i = 0; i < 4; ++i) {
                int tt = tg * 32 + wv * 4 + i;
                const u16* Pr = Pb + (size_t)tt * DHH;
                float s = 0.f;
#pragma unroll
                for (int q = 0; q < 16; ++q) {
                    int d = q * 64 + l;
                    s += tanh_fast(bf2f(Pr[d]) + hw[d]) * w2s[d];
                }
#pragma unroll
                for (int off = 32; off > 0; off >>= 1) s += __shfl_down(s, off);
                if (l == 0) ebuf[b * TENC + tt] = s;
            }
        }
        gbar(flags, gen, bt++);

        // ---------- phase C: softmax + context -> xh/xl cols 0..1023 ----------
        {
            int b = blk >> 2, dq = blk & 3;
            float* al = smem;                        // 128
            float* red = smem + 128;                 // 512
            float4* pr = (float4*)(smem + 640);      // 512 float4 = 2048 f
            float v = (tid < TENC) ? ebuf[b * TENC + tid] : -3.0e38f;
            red[tid] = v;
            __syncthreads();
            for (int s = 256; s > 0; s >>= 1) {
                if (tid < s) red[tid] = fmaxf(red[tid], red[tid + s]);
                __syncthreads();
            }
            float mx = red[0];
            __syncthreads();
            float ex = (tid < TENC) ? __expf(v - mx) : 0.f;
            red[tid] = ex;
            __syncthreads();
            for (int s = 256; s > 0; s >>= 1) {
                if (tid < s) red[tid] += red[tid + s];
                __syncthreads();
            }
            float inv = 1.f / red[0];
            if (tid < TENC) al[tid] = ex * inv;
            __syncthreads();
            const float* ep = enc + ((size_t)b * TENC + wv * 16) * DHH + dq * 256 + l * 4;
            float4 acc = {0.f, 0.f, 0.f, 0.f};
#pragma unroll 4
            for (int j = 0; j < 16; ++j) {
                float a = al[wv * 16 + j];
                float4 vv = *(const float4*)(ep + (size_t)j * DHH);
                acc.x += a * vv.x; acc.y += a * vv.y; acc.z += a * vv.z; acc.w += a * vv.w;
            }
            pr[wv * 64 + l] = acc;
            __syncthreads();
            if (tid < 64) {
                float r0 = 0.f, r1 = 0.f, r2 = 0.f, r3 = 0.f;
#pragma unroll
                for (int k = 0; k < 8; ++k) {
                    float4 a = pr[k * 64 + tid];
                    r0 += a.x; r1 += a.y; r2 += a.z; r3 += a.w;
                }
                size_t o = (size_t)b * KTOT + dq * 256 + tid * 4;
                u16 h0 = f2bf(r0), h1 = f2bf(r1), h2 = f2bf(r2), h3 = f2bf(r3);
                ushort4 hv = {h0, h1, h2, h3};
                ushort4 lv = {f2bf(r0 - bf2f(h0)), f2bf(r1 - bf2f(h1)),
                              f2bf(r2 - bf2f(h2)), f2bf(r3 - bf2f(h3))};
                *(ushort4*)&xh[o] = hv;
                *(ushort4*)&xl[o] = lv;
            }
        }
        gbar(flags, gen, bt++);

        // ---------- phase D: gates partials, per-wave tasks (272 n32 x 8 kq384) ----------
        {
            int gw = blk * 8 + wv;
            for (int task = gw; task < 2176; task += 2048) {
                int nt = task >> 3;
                int kq = task & 7;
                int kb = kq * 384;
                int n0 = nt * 32 + lr;
                const u16* wph0 = Wth + (size_t)n0 * KTOT + kb + lk4 * 8;
                const u16* wpl0 = Wtl + (size_t)n0 * KTOT + kb + lk4 * 8;
                const u16* wph1 = wph0 + (size_t)16 * KTOT;
                const u16* wpl1 = wpl0 + (size_t)16 * KTOT;
                const u16* aph = xh + (size_t)lr * KTOT + kb + lk4 * 8;
                const u16* apl = xl + (size_t)lr * KTOT + kb + lk4 * 8;
                f32x4 acc0[4] = {z, z, z, z};
                f32x4 acc1[4] = {z, z, z, z};
                for (int kk = 0; kk < 384; kk += 32) {
                    bf16x8 bh0 = *(const bf16x8*)(wph0 + kk);
                    bf16x8 bl0 = *(const bf16x8*)(wpl0 + kk);
                    bf16x8 bh1 = *(const bf16x8*)(wph1 + kk);
                    bf16x8 bl1 = *(const bf16x8*)(wpl1 + kk);
#pragma unroll
                    for (int mf = 0; mf < 4; ++mf) {
                        size_t ao = (size_t)mf * 16 * KTOT + kk;
                        bf16x8 ah = *(const bf16x8*)(aph + ao);
                        bf16x8 al_ = *(const bf16x8*)(apl + ao);
                        acc0[mf] = __builtin_amdgcn_mfma_f32_16x16x32_bf16(ah, bh0, acc0[mf], 0, 0, 0);
                        acc0[mf] = __builtin_amdgcn_mfma_f32_16x16x32_bf16(ah, bl0, acc0[mf], 0, 0, 0);
                        acc0[mf] = __builtin_amdgcn_mfma_f32_16x16x32_bf16(al_, bh0, acc0[mf], 0, 0, 0);
                        acc1[mf] = __builtin_amdgcn_mfma_f32_16x16x32_bf16(ah, bh1, acc1[mf], 0, 0, 0);
                        acc1[mf] = __builtin_amdgcn_mfma_f32_16x16x32_bf16(ah, bl1, acc1[mf], 0, 0, 0);
                        acc1[mf] = __builtin_amdgcn_mfma_f32_16x16x32_bf16(al_, bh1, acc1[mf], 0, 0, 0);
                    }
                }
                float* dst = gp + (size_t)kq * 64 * GG;
#pragma unroll
                for (int mf = 0; mf < 4; ++mf)
#pragma unroll
                    for (int r = 0; r < 4; ++r) {
                        int m = mf * 16 + lk4 * 4 + r;
                        dst[(size_t)m * GG + nt * 32 + lr] = acc0[mf][r];
                        dst[(size_t)m * GG + nt * 32 + 16 + lr] = acc1[mf][r];
                    }
            }
        }
        gbar(flags, gen, bt++);

        // ---------- phase E: gate reduce + cumsoftmax + ON-LSTM (256 blocks = 64b x 4q) ----------
        {
            int b = blk >> 2, q = blk & 3;
            float* g0 = smem;                 // 512  (gates 0..511: cum-softmax inputs)
            float* gq = smem + 512;           // 2048 (o,g,i,f slices for this quarter)
            float* cs1 = smem + 2560;         // 256
            float* cs2 = cs1 + 256;           // 256
            float* r1 = cs2 + 256;            // 256
            float* r2 = r1 + 256;             // 256
            {
                int j = tid;
                float s = bih[j] + bhh[j];
#pragma unroll
                for (int ks = 0; ks < 8; ++ks) s += gp[(size_t)(ks * 64 + b) * GG + j];
                g0[j] = s;
            }
#pragma unroll
            for (int sec = 0; sec < 4; ++sec) {
                int j = 512 + sec * 2048 + q * 512 + tid;
                float s = bih[j] + bhh[j];
#pragma unroll
                for (int ks = 0; ks < 8; ++ks) s += gp[(size_t)(ks * 64 + b) * GG + j];
                gq[sec * 512 + tid] = s;
            }
            __syncthreads();
            float x1 = 0.f, x2 = 0.f;
            if (tid < 256) { x1 = g0[tid]; x2 = g0[NCHN + tid]; r1[tid] = x1; r2[tid] = x2; }
            __syncthreads();
            for (int s = 128; s > 0; s >>= 1) {
                if (tid < s) { r1[tid] = fmaxf(r1[tid], r1[tid + s]); r2[tid] = fmaxf(r2[tid], r2[tid + s]); }
                __syncthreads();
            }
            float m1 = r1[0], m2 = r2[0];
            __syncthreads();
            float e1 = 0.f, e2 = 0.f;
            if (tid < 256) {
                e1 = __expf(x1 - m1); e2 = __expf(x2 - m2);
                r1[tid] = e1; r2[tid] = e2; cs1[tid] = e1; cs2[tid] = e2;
            }
            __syncthreads();
            for (int s = 128; s > 0; s >>= 1) {
                if (tid < s) { r1[tid] += r1[tid + s]; r2[tid] += r2[tid + s]; }
                __syncthreads();
            }
            float inv1 = 1.f / r1[0], inv2 = 1.f / r2[0];
            __syncthreads();
            for (int off = 1; off < NCHN; off <<= 1) {
                float a1 = 0.f, a2 = 0.f;
                if (tid < NCHN && tid >= off) { a1 = cs1[tid - off]; a2 = cs2[tid - off]; }
                __syncthreads();
                if (tid < NCHN) { cs1[tid] += a1; cs2[tid] += a2; }
                __syncthreads();
            }
            float* cb = c + (size_t)b * DVV;
            float* ob = out + ((size_t)b * TDEC + t) * DVV;
            u16* xhb = xh + (size_t)b * KTOT + 1024;
            u16* xlb = xl + (size_t)b * KTOT + 1024;
            {
                int idx = q * 512 + tid;
                int ch = idx >> 3;
                float cin = 1.f - cs1[ch] * inv1;
                float cfg = cs2[ch] * inv2;
                float ov = cfg * cin;
                float oo = sigmoid_fast(gq[tid]);
                float gg = tanh_fast(gq[512 + tid]);
                float ii = sigmoid_fast(gq[1024 + tid]);
                float ff = sigmoid_fast(gq[1536 + tid]);
                float fg = ff * ov + (cfg - ov);
                float ig = ii * ov + (cin - ov);
                float cy = fg * cb[idx] + ig * gg;
                cb[idx] = cy;
                float hy = oo * tanh_fast(cy);
                ob[idx] = hy;
                u16 hh = f2bf(hy);
                xhb[idx] = hh;
                xlb[idx] = f2bf(hy - bf2f(hh));
            }
        }
        gbar(flags, gen, bt++);
    }
}

// ===================== fallback multi-kernel path (round-3 style) =====================

__global__ __launch_bounds__(512) void k_mma1(const u16* __restrict__ xh,
                                              const u16* __restrict__ Wta,
                                              float* __restrict__ hWp) {
    __shared__ float red[64 * 68];
    int n0 = blockIdx.x * 64;
    int kseg = blockIdx.y;                 // 8 segs of 256
    int tid = threadIdx.x;
    int wv = tid >> 6, l = tid & 63;
    int wn = wv & 3, kh = wv >> 2;
    int lr = l & 15, lk = (l >> 4) * 8;
    int n = n0 + wn * 16 + lr;
    const u16* wp = Wta + (size_t)n * 2048 + lk;
    const u16* ap = xh + (size_t)lr * KTOT + 1024 + lk;
    f32x4 z = {0.f, 0.f, 0.f, 0.f};
    f32x4 acc[4] = {z, z, z, z};
    int kbeg = kseg * 256 + kh * 128;
    for (int k = kbeg; k < kbeg + 128; k += 32) {
        bf16x8 bfrag = *(const bf16x8*)(wp + k);
#pragma unroll
        for (int mf = 0; mf < 4; ++mf) {
            bf16x8 a = *(const bf16x8*)(ap + (size_t)mf * 16 * KTOT + k);
            acc[mf] = __builtin_amdgcn_mfma_f32_16x16x32_bf16(a, bfrag, acc[mf], 0, 0, 0);
        }
    }
    int moff = (l >> 4) * 4;
    if (kh == 0) {
#pragma unroll
        for (int mf = 0; mf < 4; ++mf)
#pragma unroll
            for (int r = 0; r < 4; ++r)
                red[(mf * 16 + moff + r) * 68 + wn * 16 + lr] = acc[mf][r];
    }
    __syncthreads();
    if (kh == 1) {
        float* dst = hWp + (size_t)kseg * 64 * DHH;
#pragma unroll
        for (int mf = 0; mf < 4; ++mf)
#pragma unroll
            for (int r = 0; r < 4; ++r) {
                int m = mf * 16 + moff + r;
                dst[(size_t)m * DHH + n] = acc[mf][r] + red[m * 68 + wn * 16 + lr];
            }
    }
}

__global__ __launch_bounds__(256) void k_e_bf(const u16* __restrict__ Pbf,
                                              const float* __restrict__ hWp,
                                              const float* __restrict__ w2,
                                              float* __restrict__ e) {
    int b = blockIdx.x, tg = blockIdx.y;
    __shared__ float hw[DHH];
    __shared__ float w2s[DHH];
    int tid = threadIdx.x;
    {
        float4 s = {0.f, 0.f, 0.f, 0.f};
#pragma unroll
        for (int ks = 0; ks < 8; ++ks) {
            float4 v = *(const float4*)&hWp[(size_t)(ks * 64 + b) * DHH + tid * 4];
            s.x += v.x; s.y += v.y; s.z += v.z; s.w += v.w;
        }
        *(float4*)&hw[tid * 4] = s;
        *(float4*)&w2s[tid * 4] = *(const float4*)&w2[tid * 4];
    }
    __syncthreads();
    int wave = tid >> 6, lane = tid & 63;
    const u16* Pb = Pbf + (size_t)b * TENC * DHH;
    for (int tt = 0; tt < 8; ++tt) {
        int t = tg * 32 + wave * 8 + tt;
        const u16* Pr = Pb + (size_t)t * DHH;
        float s = 0.f;
#pragma unroll
        for (int i = 0; i < 16; ++i) {
            int d = i * 64 + lane;
            s += tanh_fast(bf2f(Pr[d]) + hw[d]) * w2s[d];
        }
#pragma unroll
        for (int off = 32; off > 0; off >>= 1) s += __shfl_down(s, off);
        if (lane == 0) e[b * TENC + t] = s;
    }
}

__global__ __launch_bounds__(256) void k_sc2(const float* __restrict__ e,
                                             const float* __restrict__ enc,
                                             u16* __restrict__ xh,
                                             u16* __restrict__ xl) {
    int b = blockIdx.x, dq = blockIdx.y;
    __shared__ float al[TENC];
    __shared__ float red[256];
    __shared__ float4 pr[4][64];
    int tid = threadIdx.x;
    float v = (tid < TENC) ? e[b * TENC + tid] : -3.0e38f;
    red[tid] = v;
    __syncthreads();
    for (int s = 128; s > 0; s >>= 1) {
        if (tid < s) red[tid] = fmaxf(red[tid], red[tid + s]);
        __syncthreads();
    }
    float mx = red[0];
    __syncthreads();
    float ex = (tid < TENC) ? __expf(v - mx) : 0.f;
    red[tid] = ex;
    __syncthreads();
    for (int s = 128; s > 0; s >>= 1) {
        if (tid < s) red[tid] += red[tid + s];
        __syncthreads();
    }
    float inv = 1.f / red[0];
    if (tid < TENC) al[tid] = ex * inv;
    __syncthreads();
    int w = tid >> 6, l = tid & 63;
    int dbase = dq * 256 + l * 4;
    const float* ep = enc + ((size_t)b * TENC + w * 32) * DHH + dbase;
    float4 acc = {0.f, 0.f, 0.f, 0.f};
#pragma unroll 8
    for (int tt = 0; tt < 32; ++tt) {
        float a = al[w * 32 + tt];
        float4 vv = *(const float4*)(ep + (size_t)tt * DHH);
        acc.x += a * vv.x; acc.y += a * vv.y; acc.z += a * vv.z; acc.w += a * vv.w;
    }
    pr[w][l] = acc;
    __syncthreads();
    if (tid < 64) {
        float4 a0 = pr[0][tid], a1 = pr[1][tid], a2 = pr[2][tid], a3 = pr[3][tid];
        float r0 = a0.x + a1.x + a2.x + a3.x;
        float r1 = a0.y + a1.y + a2.y + a3.y;
        float r2 = a0.z + a1.z + a2.z + a3.z;
        float r3 = a0.w + a1.w + a2.w + a3.w;
        size_t o = (size_t)b * KTOT + dq * 256 + tid * 4;
        u16 h0 = f2bf(r0), h1 = f2bf(r1), h2 = f2bf(r2), h3 = f2bf(r3);
        ushort4 hv = {h0, h1, h2, h3};
        ushort4 lv = {f2bf(r0 - bf2f(h0)), f2bf(r1 - bf2f(h1)),
                      f2bf(r2 - bf2f(h2)), f2bf(r3 - bf2f(h3))};
        *(ushort4*)&xh[o] = hv;
        *(ushort4*)&xl[o] = lv;
    }
}

template <int SEG>
__global__ __launch_bounds__(512) void k_mma3(const u16* __restrict__ xh,
                                              const u16* __restrict__ xl,
                                              const u16* __restrict__ Wh,
                                              const u16* __restrict__ Wl,
                                              float* __restrict__ part) {
    __shared__ float red[64 * 68];
    int n0 = blockIdx.x * 64;
    int kseg = blockIdx.y;
    int tid = threadIdx.x;
    int wv = tid >> 6, l = tid & 63;
    int wn = wv & 3, kh = wv >> 2;
    int lr = l & 15, lk = (l >> 4) * 8;
    int n = n0 + wn * 16 + lr;
    const u16* wph = Wh + (size_t)n * KTOT + lk;
    const u16* wpl = Wl + (size_t)n * KTOT + lk;
    const u16* aph = xh + (size_t)lr * KTOT + lk;
    const u16* apl = xl + (size_t)lr * KTOT + lk;
    f32x4 z = {0.f, 0.f, 0.f, 0.f};
    f32x4 acc[4] = {z, z, z, z};
    const int KSEG = KTOT / SEG;
    const int KH = KSEG / 2;
    int kbeg = kseg * KSEG + kh * KH;
    for (int k = kbeg; k < kbeg + KH; k += 32) {
        bf16x8 bh = *(const bf16x8*)(wph + k);
        bf16x8 bl = *(const bf16x8*)(wpl + k);
#pragma unroll
        for (int mf = 0; mf < 4; ++mf) {
            size_t ao = (size_t)mf * 16 * KTOT + k;
            bf16x8 ah = *(const bf16x8*)(aph + ao);
            bf16x8 al = *(const bf16x8*)(apl + ao);
            acc[mf] = __builtin_amdgcn_mfma_f32_16x16x32_bf16(ah, bh, acc[mf], 0, 0, 0);
            acc[mf] = __builtin_amdgcn_mfma_f32_16x16x32_bf16(ah, bl, acc[mf], 0, 0, 0);
            acc[mf] = __builtin_amdgcn_mfma_f32_16x16x32_bf16(al, bh, acc[mf], 0, 0, 0);
        }
    }
    int moff = (l >> 4) * 4;
    if (kh == 0) {
#pragma unroll
        for (int mf = 0; mf < 4; ++mf)
#pragma unroll
            for (int r = 0; r < 4; ++r)
                red[(mf * 16 + moff + r) * 68 + wn * 16 + lr] = acc[mf][r];
    }
    __syncthreads();
    if (kh == 1) {
        float* dst = part + (size_t)kseg * 64 * GG;
#pragma unroll
        for (int mf = 0; mf < 4; ++mf)
#pragma unroll
            for (int r = 0; r < 4; ++r) {
                int m = mf * 16 + moff + r;
                dst[(size_t)m * GG + n] = acc[mf][r] + red[m * 68 + wn * 16 + lr];
            }
    }
}

__global__ __launch_bounds__(256) void k_pw2(const float* __restrict__ part, int nseg,
                                             const float* __restrict__ bih,
                                             const float* __restrict__ bhh,
                                             u16* __restrict__ xh,
                                             u16* __restrict__ xl,
                                             float* __restrict__ c,
                                             float* __restrict__ out, int t) {
    int b = blockIdx.x;
    __shared__ float g[GG];
    __shared__ float cs1[NCHN], cs2[NCHN], t1[NCHN], t2[NCHN];
    int tid = threadIdx.x;
    for (int p = 0; p < 34; ++p) {
        int j = p * 256 + tid;
        float s = bih[j] + bhh[j];
        for (int ks = 0; ks < nseg; ++ks) s += part[(size_t)(ks * 64 + b) * GG + j];
        g[j] = s;
    }
    __syncthreads();
    float x1 = g[tid], x2 = g[NCHN + tid];
    t1[tid] = x1; t2[tid] = x2;
    __syncthreads();
    for (int s = 128; s > 0; s >>= 1) {
        if (tid < s) { t1[tid] = fmaxf(t1[tid], t1[tid + s]); t2[tid] = fmaxf(t2[tid], t2[tid + s]); }
        __syncthreads();
    }
    float m1 = t1[0], m2 = t2[0];
    __syncthreads();
    float e1 = __expf(x1 - m1), e2 = __expf(x2 - m2);
    t1[tid] = e1; t2[tid] = e2;
    __syncthreads();
    for (int s = 128; s > 0; s >>= 1) {
        if (tid < s) { t1[tid] += t1[tid + s]; t2[tid] += t2[tid + s]; }
        __syncthreads();
    }
    float inv1 = 1.f / t1[0], inv2 = 1.f / t2[0];
    __syncthreads();
    cs1[tid] = e1; cs2[tid] = e2;
    __syncthreads();
    for (int off = 1; off < NCHN; off <<= 1) {
        float a1 = (tid >= off) ? cs1[tid - off] : 0.f;
        float a2 = (tid >= off) ? cs2[tid - off] : 0.f;
        __syncthreads();
        cs1[tid] += a1; cs2[tid] += a2;
        __syncthreads();
    }
    float* cb = c + (size_t)b * DVV;
    float* ob = out + ((size_t)b * TDEC + t) * DVV;
    u16* xhb = xh + (size_t)b * KTOT + 1024;
    u16* xlb = xl + (size_t)b * KTOT + 1024;
    for (int p = 0; p < 8; ++p) {
        int idx = p * 256 + tid;
        int ch = idx >> 3;
        float cin = 1.f - cs1[ch] * inv1;
        float cfg = cs2[ch] * inv2;
        float ov = cfg * cin;
        float oo = sigmoid_fast(g[512 + idx]);
        float gg = tanh_fast(g[2560 + idx]);
        float ii = sigmoid_fast(g[4608 + idx]);
        float ff = sigmoid_fast(g[6656 + idx]);
        float fg = ff * ov + (cfg - ov);
        float ig = ii * ov + (cin - ov);
        float cy = fg * cb[idx] + ig * gg;
        cb[idx] = cy;
        float hy = oo * tanh_fast(cy);
        ob[idx] = hy;
        u16 hh = f2bf(hy);
        xhb[idx] = hh;
        xlb[idx] = f2bf(hy - bf2f(hh));
    }
}

// ===================== launch =====================

extern "C" void kernel_launch(void* const* d_in, const int* in_sizes, int n_in,
                              void* d_out, int out_size, void* d_ws, size_t ws_size,
                              hipStream_t stream) {
    const float* enc    = (const float*)d_in[0];
    const float* W_att1 = (const float*)d_in[2];
    const float* b_att1 = (const float*)d_in[3];
    const float* w_att2 = (const float*)d_in[4];
    const float* W_ih   = (const float*)d_in[5];
    const float* b_ih   = (const float*)d_in[6];
    const float* W_hh   = (const float*)d_in[7];
    const float* b_hh   = (const float*)d_in[8];
    float* out = (float*)d_out;
    float* ws  = (float*)d_ws;
    const float* Wh_att = W_att1 + 1024 * 1024;

    // layout (151,323,648 B total)
    float* hWp  = ws;                          // 16*64*1024 = 1,048,576 f
    float* ebuf = hWp + 1048576;               // 8,192 f
    float* gp   = ebuf + 8192;                 // 8*64*8704 = 4,456,448 f
    float* c    = gp + 4456448;                // 131,072 f
    int*   bar  = (int*)(c + 131072);          // 8,448 ints (flags + gen)
    u16* Pbf = (u16*)(bar + 8448);             // 8,388,608
    u16* xh  = Pbf + 8388608;                  // 196,608
    u16* xl  = xh + 196608;                    // 196,608
    u16* Wth = xl + 196608;                    // 26,738,688
    u16* Wtl = Wth + 26738688;                 // 26,738,688
    u16* Wta = Wtl + 26738688;                 // 2,097,152
    if (ws_size < 151323648ull) return;

    // precompute (one-time per call)
    k_cvt<true><<<dim3(136, 48), 256, 0, stream>>>(W_ih, W_hh, 1024, GG, KTOT, Wth, Wtl);
    k_cvt<false><<<dim3(16, 32), 256, 0, stream>>>(Wh_att, Wh_att, 2048, DHH, 2048, Wta, Wta);
    k_Pb<<<dim3(16, 128), 256, 0, stream>>>(enc, W_att1, b_att1, Pbf);
    k_init2<<<768, 256, 0, stream>>>(c, xh, xl, bar);

    // persistent cooperative decode
    void* args[] = {(void*)&Pbf, (void*)&hWp, (void*)&ebuf, (void*)&gp, (void*)&c,
                    (void*)&xh, (void*)&xl, (void*)&Wth, (void*)&Wtl, (void*)&Wta,
                    (void*)&enc, (void*)&w_att2, (void*)&b_ih, (void*)&b_hh,
                    (void*)&out, (void*)&bar};
    hipError_t err = hipLaunchCooperativeKernel((const void*)k_decode,
                                                dim3(256), dim3(512), args, 0, stream);
    if (err != hipSuccess) {
        (void)hipGetLastError();
        // fallback: multi-kernel loop (correct, slower)
        for (int t = 0; t < TDEC; ++t) {
            k_mma1<<<dim3(16, 8), 512, 0, stream>>>(xh, Wta, hWp);
            k_e_bf<<<dim3(BB, 4), 256, 0, stream>>>(Pbf, hWp, w_att2, ebuf);
            k_sc2<<<dim3(BB, 4), 256, 0, stream>>>(ebuf, enc, xh, xl);
            k_mma3<4><<<dim3(136, 4), 512, 0, stream>>>(xh, xl, Wth, Wtl, gp);
            k_pw2<<<BB, 256, 0, stream>>>(gp, 4, b_ih, b_hh, xh, xl, c, out, t);
        }
    }
}

// Round 6
// 25092.891 us; speedup vs baseline: 2.4037x; 2.4037x over previous
//
#include <hip/hip_runtime.h>
#include <math.h>

#define BB   64
#define TENC 128
#define TDEC 64
#define DHH  1024
#define DVV  2048
#define NCHN 256
#define GG   8704   // 4*DV + 2*NCH
#define KTOT 3072   // DH + DV

typedef unsigned short u16;
typedef __bf16 bf16x8 __attribute__((ext_vector_type(8)));
typedef float  f32x4  __attribute__((ext_vector_type(4)));

__device__ __forceinline__ u16 f2bf(float f) {
    unsigned u = __float_as_uint(f);
    unsigned r = (u + 0x7fffu + ((u >> 16) & 1u)) >> 16;
    return (u16)r;
}
__device__ __forceinline__ float bf2f(u16 s) { return __uint_as_float(((unsigned)s) << 16); }
__device__ __forceinline__ float tanh_fast(float x) {
    float xc = fminf(fmaxf(x, -15.f), 15.f);
    float t = __expf(2.f * xc);
    return 1.f - 2.f * __builtin_amdgcn_rcpf(t + 1.f);
}
__device__ __forceinline__ float sigmoid_fast(float x) {
    float xc = fminf(fmaxf(x, -30.f), 30.f);
    return __builtin_amdgcn_rcpf(1.f + __expf(-xc));
}

// ---- grid barrier: relaxed polls, ONE release + ONE acquire fence per barrier ----
// Round-5 bug: acquire-load in the spin loop emits buffer_inv per poll -> cache
// invalidate storm across all XCDs. Here all polls are RELAXED (no cache ops);
// the release fence (buffer_wbl2) runs once before flagging, the acquire fence
// (buffer_inv) runs once after the spin exits.
__device__ __forceinline__ void gbar(int* flags, int* gen, int target) {
    __syncthreads();   // compiler emits s_waitcnt vmcnt(0) before s_barrier -> all waves' stores done
    int tid = threadIdx.x;
    if (tid == 0) {
        __builtin_amdgcn_fence(__ATOMIC_RELEASE, "agent");   // L2 writeback, once
        __hip_atomic_store(flags + blockIdx.x * 32, target,
                           __ATOMIC_RELAXED, __HIP_MEMORY_SCOPE_AGENT);
    }
    if (blockIdx.x == 0) {
        if (tid < 64) {
#pragma unroll
            for (int i = 0; i < 4; ++i) {
                int idx = (tid * 4 + i) * 32;
                while (__hip_atomic_load(flags + idx, __ATOMIC_RELAXED,
                                         __HIP_MEMORY_SCOPE_AGENT) < target)
                    __builtin_amdgcn_s_sleep(4);
            }
        }
        __syncthreads();
        if (tid == 0)
            __hip_atomic_store(gen, target, __ATOMIC_RELAXED, __HIP_MEMORY_SCOPE_AGENT);
    } else if (tid == 0) {
        while (__hip_atomic_load(gen, __ATOMIC_RELAXED,
                                 __HIP_MEMORY_SCOPE_AGENT) < target)
            __builtin_amdgcn_s_sleep(4);
    }
    if (tid == 0)
        __builtin_amdgcn_fence(__ATOMIC_ACQUIRE, "agent");   // L1/L2 invalidate, once
    __syncthreads();
}

// ===================== precompute kernels =====================

__global__ __launch_bounds__(256) void k_init2(float* c, u16* xh, u16* xl, int* bar) {
    int i = blockIdx.x * 256 + threadIdx.x;   // grid 768 -> 196608
    xh[i] = 0; xl[i] = 0;
    if (i < BB * DVV) c[i] = 0.f;
    if (i < 8448) bar[i] = 0;
}

// transpose+convert: D[n][k] = bf16(S[k][n]) (hi, optionally lo residual)
template <bool LO>
__global__ __launch_bounds__(256) void k_cvt(const float* __restrict__ S1,
                                             const float* __restrict__ S2,
                                             int K1, int N, int K,
                                             u16* __restrict__ Dh,
                                             u16* __restrict__ Dl) {
    __shared__ float t[64][65];
    int n0 = blockIdx.x * 64, k0 = blockIdx.y * 64;
    int tid = threadIdx.x;
    int cn = tid & 63, r4 = tid >> 6;
#pragma unroll
    for (int p = 0; p < 16; ++p) {
        int kk = p * 4 + r4;
        int kg = k0 + kk;
        const float* src = (kg < K1) ? S1 + (size_t)kg * N : S2 + (size_t)(kg - K1) * N;
        t[kk][cn] = src[n0 + cn];
    }
    __syncthreads();
    int ck = tid & 63, n4 = tid >> 6;
#pragma unroll
    for (int p = 0; p < 16; ++p) {
        int nn = p * 4 + n4;
        float w = t[ck][nn];
        u16 hi = f2bf(w);
        size_t o = (size_t)(n0 + nn) * K + k0 + ck;
        Dh[o] = hi;
        if (LO) Dl[o] = f2bf(w - bf2f(hi));
    }
}

// P = enc @ W1[:DH] + b1, f32 SMEM GEMM, bf16 store
__global__ __launch_bounds__(256) void k_Pb(const float* __restrict__ enc,
                                            const float* __restrict__ W1,
                                            const float* __restrict__ b1,
                                            u16* __restrict__ Pb) {
    __shared__ float As[32][68];
    __shared__ float Bs[32][68];
    int j0 = blockIdx.x * 64;
    int m0 = blockIdx.y * 64;
    int tid = threadIdx.x;
    int jg = tid & 15, bg = tid >> 4;
    float acc[4][4] = {};
    for (int k0 = 0; k0 < DHH; k0 += 32) {
#pragma unroll
        for (int p = 0; p < 8; ++p) {
            int r = p * 8 + (tid >> 5);
            int kk = tid & 31;
            As[kk][r] = enc[(size_t)(m0 + r) * DHH + k0 + kk];
        }
#pragma unroll
        for (int p = 0; p < 8; ++p) {
            int kk = p * 4 + (tid >> 6);
            int jl = tid & 63;
            Bs[kk][jl] = W1[(size_t)(k0 + kk) * DHH + j0 + jl];
        }
        __syncthreads();
#pragma unroll
        for (int kk = 0; kk < 32; ++kk) {
            float4 a = *(const float4*)&As[kk][bg * 4];
            float4 b = *(const float4*)&Bs[kk][jg * 4];
            float av[4] = {a.x, a.y, a.z, a.w};
            float bv[4] = {b.x, b.y, b.z, b.w};
#pragma unroll
            for (int i = 0; i < 4; ++i)
#pragma unroll
                for (int j = 0; j < 4; ++j) acc[i][j] += av[i] * bv[j];
        }
        __syncthreads();
    }
    float4 bb = *(const float4*)&b1[j0 + jg * 4];
    float bia[4] = {bb.x, bb.y, bb.z, bb.w};
#pragma unroll
    for (int i = 0; i < 4; ++i) {
        int r = m0 + bg * 4 + i;
        ushort4 sv;
        sv.x = f2bf(acc[i][0] + bia[0]);
        sv.y = f2bf(acc[i][1] + bia[1]);
        sv.z = f2bf(acc[i][2] + bia[2]);
        sv.w = f2bf(acc[i][3] + bia[3]);
        *(ushort4*)&Pb[(size_t)r * DHH + j0 + jg * 4] = sv;
    }
}

// ===================== persistent decode kernel =====================
// 4 barriers/step: A (hW MFMA) | BC (e+softmax+ctx, per-batch) | D (gates MFMA) | E (pointwise)

__global__ __launch_bounds__(512) void k_decode(
        const u16* Pbf, float* hWp, float* ebuf, float* gp, float* c,
        u16* xh, u16* xl,
        const u16* __restrict__ Wth, const u16* __restrict__ Wtl,
        const u16* __restrict__ Wta,
        const float* __restrict__ enc, const float* __restrict__ w2,
        const float* __restrict__ bih, const float* __restrict__ bhh,
        float* out, int* bar) {
    __shared__ float smem[11008];   // 44 KB, reused per phase
    int* flags = bar;
    int* gen = bar + 8192;
    int blk = blockIdx.x, tid = threadIdx.x;
    int wv = tid >> 6, l = tid & 63;
    int lr = l & 15, lk4 = l >> 4;
    f32x4 z = {0.f, 0.f, 0.f, 0.f};
    int bt = 1;

    for (int t = 0; t < TDEC; ++t) {
        // ---------- phase A: hW partials (16 n-tiles x 16 ksegs of 128) ----------
        {
            int nt = blk & 15, kseg = blk >> 4;
            int wn = wv & 3, kh = wv >> 2;
            int n = nt * 64 + wn * 16 + lr;
            int kb = kseg * 128 + kh * 64;
            const u16* wp = Wta + (size_t)n * 2048 + kb + lk4 * 8;
            const u16* ap = xh + (size_t)lr * KTOT + 1024 + kb + lk4 * 8;
            f32x4 acc[4] = {z, z, z, z};
#pragma unroll
            for (int kk = 0; kk < 64; kk += 32) {
                bf16x8 bfrag = *(const bf16x8*)(wp + kk);
#pragma unroll
                for (int mf = 0; mf < 4; ++mf) {
                    bf16x8 a = *(const bf16x8*)(ap + (size_t)mf * 16 * KTOT + kk);
                    acc[mf] = __builtin_amdgcn_mfma_f32_16x16x32_bf16(a, bfrag, acc[mf], 0, 0, 0);
                }
            }
            float* red = smem;   // 64 x 68
            if (kh == 0) {
#pragma unroll
                for (int mf = 0; mf < 4; ++mf)
#pragma unroll
                    for (int r = 0; r < 4; ++r)
                        red[(mf * 16 + lk4 * 4 + r) * 68 + wn * 16 + lr] = acc[mf][r];
            }
            __syncthreads();
            if (kh == 1) {
#pragma unroll
                for (int mf = 0; mf < 4; ++mf)
#pragma unroll
                    for (int r = 0; r < 4; ++r) {
                        int m = mf * 16 + lk4 * 4 + r;
                        hWp[(size_t)(kseg * 64 + m) * DHH + n] =
                            acc[mf][r] + red[m * 68 + wn * 16 + lr];
                    }
            }
        }
        gbar(flags, gen, bt++);

        // ---------- phase BC (blocks 0..63 = batch b): e, softmax, context ----------
        if (blk < BB) {
            int b = blk;
            float* hw  = smem;            // 1024
            float* w2s = smem + 1024;     // 1024
            float* er  = smem + 2048;     // 128
            float* al  = smem + 2176;     // 128
            float* red = smem + 2304;     // 512
            float* pr  = smem + 2816;     // 8192
            // reduce 16 hW partials + stage w2
#pragma unroll
            for (int p = 0; p < 2; ++p) {
                int d = p * 512 + tid;
                float s = 0.f;
#pragma unroll
                for (int ks = 0; ks < 16; ++ks) s += hWp[(size_t)(ks * 64 + b) * DHH + d];
                hw[d] = s;
                w2s[d] = w2[d];
            }
            __syncthreads();
            // e[b, t]: wave wv handles t = wv*16 .. wv*16+15
            const u16* Pb = Pbf + (size_t)b * TENC * DHH;
#pragma unroll
            for (int i = 0; i < 16; ++i) {
                int tt = wv * 16 + i;
                const u16* Pr = Pb + (size_t)tt * DHH;
                float s = 0.f;
#pragma unroll
                for (int q = 0; q < 16; ++q) {
                    int d = q * 64 + l;
                    s += tanh_fast(bf2f(Pr[d]) + hw[d]) * w2s[d];
                }
#pragma unroll
                for (int off = 32; off > 0; off >>= 1) s += __shfl_down(s, off);
                if (l == 0) er[tt] = s;
            }
            __syncthreads();
            // softmax over 128 t
            float v = (tid < TENC) ? er[tid] : -3.0e38f;
            red[tid] = v;
            __syncthreads();
            for (int s = 256; s > 0; s >>= 1) {
                if (tid < s) red[tid] = fmaxf(red[tid], red[tid + s]);
                __syncthreads();
            }
            float mx = red[0];
            __syncthreads();
            float ex = (tid < TENC) ? __expf(v - mx) : 0.f;
            red[tid] = ex;
            __syncthreads();
            for (int s = 256; s > 0; s >>= 1) {
                if (tid < s) red[tid] += red[tid + s];
                __syncthreads();
            }
            float inv = 1.f / red[0];
            if (tid < TENC) al[tid] = ex * inv;
            __syncthreads();
            // context: wave wv accumulates its 16 t rows over all 1024 d
            float acc[16];
#pragma unroll
            for (int j = 0; j < 16; ++j) acc[j] = 0.f;
            const float* eb = enc + (size_t)b * TENC * DHH;
            for (int i = 0; i < 16; ++i) {
                int tt = wv * 16 + i;
                float a = al[tt];
                const float* row = eb + (size_t)tt * DHH;
#pragma unroll
                for (int j = 0; j < 16; ++j) acc[j] += a * row[j * 64 + l];
            }
#pragma unroll
            for (int j = 0; j < 16; ++j) pr[wv * 1024 + j * 64 + l] = acc[j];
            __syncthreads();
            // reduce 8 wave partials, write ctx as bf16 hi/lo
#pragma unroll
            for (int p = 0; p < 2; ++p) {
                int d = p * 512 + tid;
                float s = 0.f;
#pragma unroll
                for (int w = 0; w < 8; ++w) s += pr[w * 1024 + d];
                u16 hh = f2bf(s);
                xh[(size_t)b * KTOT + d] = hh;
                xl[(size_t)b * KTOT + d] = f2bf(s - bf2f(hh));
            }
        }
        gbar(flags, gen, bt++);

        // ---------- phase D: gates partials, per-wave tasks (272 n32 x 8 kq384) ----------
        {
            int gw = blk * 8 + wv;
            for (int task = gw; task < 2176; task += 2048) {
                int nt = task >> 3;
                int kq = task & 7;
                int kb = kq * 384;
                int n0 = nt * 32 + lr;
                const u16* wph0 = Wth + (size_t)n0 * KTOT + kb + lk4 * 8;
                const u16* wpl0 = Wtl + (size_t)n0 * KTOT + kb + lk4 * 8;
                const u16* wph1 = wph0 + (size_t)16 * KTOT;
                const u16* wpl1 = wpl0 + (size_t)16 * KTOT;
                const u16* aph = xh + (size_t)lr * KTOT + kb + lk4 * 8;
                const u16* apl = xl + (size_t)lr * KTOT + kb + lk4 * 8;
                f32x4 acc0[4] = {z, z, z, z};
                f32x4 acc1[4] = {z, z, z, z};
                for (int kk = 0; kk < 384; kk += 32) {
                    bf16x8 bh0 = *(const bf16x8*)(wph0 + kk);
                    bf16x8 bl0 = *(const bf16x8*)(wpl0 + kk);
                    bf16x8 bh1 = *(const bf16x8*)(wph1 + kk);
                    bf16x8 bl1 = *(const bf16x8*)(wpl1 + kk);
#pragma unroll
                    for (int mf = 0; mf < 4; ++mf) {
                        size_t ao = (size_t)mf * 16 * KTOT + kk;
                        bf16x8 ah = *(const bf16x8*)(aph + ao);
                        bf16x8 al_ = *(const bf16x8*)(apl + ao);
                        acc0[mf] = __builtin_amdgcn_mfma_f32_16x16x32_bf16(ah, bh0, acc0[mf], 0, 0, 0);
                        acc0[mf] = __builtin_amdgcn_mfma_f32_16x16x32_bf16(ah, bl0, acc0[mf], 0, 0, 0);
                        acc0[mf] = __builtin_amdgcn_mfma_f32_16x16x32_bf16(al_, bh0, acc0[mf], 0, 0, 0);
                        acc1[mf] = __builtin_amdgcn_mfma_f32_16x16x32_bf16(ah, bh1, acc1[mf], 0, 0, 0);
                        acc1[mf] = __builtin_amdgcn_mfma_f32_16x16x32_bf16(ah, bl1, acc1[mf], 0, 0, 0);
                        acc1[mf] = __builtin_amdgcn_mfma_f32_16x16x32_bf16(al_, bh1, acc1[mf], 0, 0, 0);
                    }
                }
                float* dst = gp + (size_t)kq * 64 * GG;
#pragma unroll
                for (int mf = 0; mf < 4; ++mf)
#pragma unroll
                    for (int r = 0; r < 4; ++r) {
                        int m = mf * 16 + lk4 * 4 + r;
                        dst[(size_t)m * GG + nt * 32 + lr] = acc0[mf][r];
                        dst[(size_t)m * GG + nt * 32 + 16 + lr] = acc1[mf][r];
                    }
            }
        }
        gbar(flags, gen, bt++);

        // ---------- phase E: gate reduce + cumsoftmax + ON-LSTM (256 blocks = 64b x 4q) ----------
        {
            int b = blk >> 2, q = blk & 3;
            float* g0 = smem;                 // 512
            float* gq = smem + 512;           // 2048
            float* cs1 = smem + 2560;         // 256
            float* cs2 = cs1 + 256;           // 256
            float* r1 = cs2 + 256;            // 256
            float* r2 = r1 + 256;             // 256
            {
                int j = tid;
                float s = bih[j] + bhh[j];
#pragma unroll
                for (int ks = 0; ks < 8; ++ks) s += gp[(size_t)(ks * 64 + b) * GG + j];
                g0[j] = s;
            }
#pragma unroll
            for (int sec = 0; sec < 4; ++sec) {
                int j = 512 + sec * 2048 + q * 512 + tid;
                float s = bih[j] + bhh[j];
#pragma unroll
                for (int ks = 0; ks < 8; ++ks) s += gp[(size_t)(ks * 64 + b) * GG + j];
                gq[sec * 512 + tid] = s;
            }
            __syncthreads();
            float x1 = 0.f, x2 = 0.f;
            if (tid < 256) { x1 = g0[tid]; x2 = g0[NCHN + tid]; r1[tid] = x1; r2[tid] = x2; }
            __syncthreads();
            for (int s = 128; s > 0; s >>= 1) {
                if (tid < s) { r1[tid] = fmaxf(r1[tid], r1[tid + s]); r2[tid] = fmaxf(r2[tid], r2[tid + s]); }
                __syncthreads();
            }
            float m1 = r1[0], m2 = r2[0];
            __syncthreads();
            float e1 = 0.f, e2 = 0.f;
            if (tid < 256) {
                e1 = __expf(x1 - m1); e2 = __expf(x2 - m2);
                r1[tid] = e1; r2[tid] = e2; cs1[tid] = e1; cs2[tid] = e2;
            }
            __syncthreads();
            for (int s = 128; s > 0; s >>= 1) {
                if (tid < s) { r1[tid] += r1[tid + s]; r2[tid] += r2[tid + s]; }
                __syncthreads();
            }
            float inv1 = 1.f / r1[0], inv2 = 1.f / r2[0];
            __syncthreads();
            for (int off = 1; off < NCHN; off <<= 1) {
                float a1 = 0.f, a2 = 0.f;
                if (tid < NCHN && tid >= off) { a1 = cs1[tid - off]; a2 = cs2[tid - off]; }
                __syncthreads();
                if (tid < NCHN) { cs1[tid] += a1; cs2[tid] += a2; }
                __syncthreads();
            }
            float* cb = c + (size_t)b * DVV;
            float* ob = out + ((size_t)b * TDEC + t) * DVV;
            u16* xhb = xh + (size_t)b * KTOT + 1024;
            u16* xlb = xl + (size_t)b * KTOT + 1024;
            {
                int idx = q * 512 + tid;
                int ch = idx >> 3;
                float cin = 1.f - cs1[ch] * inv1;
                float cfg = cs2[ch] * inv2;
                float ov = cfg * cin;
                float oo = sigmoid_fast(gq[tid]);
                float gg = tanh_fast(gq[512 + tid]);
                float ii = sigmoid_fast(gq[1024 + tid]);
                float ff = sigmoid_fast(gq[1536 + tid]);
                float fg = ff * ov + (cfg - ov);
                float ig = ii * ov + (cin - ov);
                float cy = fg * cb[idx] + ig * gg;
                cb[idx] = cy;
                float hy = oo * tanh_fast(cy);
                ob[idx] = hy;
                u16 hh = f2bf(hy);
                xhb[idx] = hh;
                xlb[idx] = f2bf(hy - bf2f(hh));
            }
        }
        gbar(flags, gen, bt++);
    }
}

// ===================== fallback multi-kernel path (round-3 style) =====================

__global__ __launch_bounds__(512) void k_mma1(const u16* __restrict__ xh,
                                              const u16* __restrict__ Wta,
                                              float* __restrict__ hWp) {
    __shared__ float red[64 * 68];
    int n0 = blockIdx.x * 64;
    int kseg = blockIdx.y;                 // 8 segs of 256
    int tid = threadIdx.x;
    int wv = tid >> 6, l = tid & 63;
    int wn = wv & 3, kh = wv >> 2;
    int lr = l & 15, lk = (l >> 4) * 8;
    int n = n0 + wn * 16 + lr;
    const u16* wp = Wta + (size_t)n * 2048 + lk;
    const u16* ap = xh + (size_t)lr * KTOT + 1024 + lk;
    f32x4 z = {0.f, 0.f, 0.f, 0.f};
    f32x4 acc[4] = {z, z, z, z};
    int kbeg = kseg * 256 + kh * 128;
    for (int k = kbeg; k < kbeg + 128; k += 32) {
        bf16x8 bfrag = *(const bf16x8*)(wp + k);
#pragma unroll
        for (int mf = 0; mf < 4; ++mf) {
            bf16x8 a = *(const bf16x8*)(ap + (size_t)mf * 16 * KTOT + k);
            acc[mf] = __builtin_amdgcn_mfma_f32_16x16x32_bf16(a, bfrag, acc[mf], 0, 0, 0);
        }
    }
    int moff = (l >> 4) * 4;
    if (kh == 0) {
#pragma unroll
        for (int mf = 0; mf < 4; ++mf)
#pragma unroll
            for (int r = 0; r < 4; ++r)
                red[(mf * 16 + moff + r) * 68 + wn * 16 + lr] = acc[mf][r];
    }
    __syncthreads();
    if (kh == 1) {
        float* dst = hWp + (size_t)kseg * 64 * DHH;
#pragma unroll
        for (int mf = 0; mf < 4; ++mf)
#pragma unroll
            for (int r = 0; r < 4; ++r) {
                int m = mf * 16 + moff + r;
                dst[(size_t)m * DHH + n] = acc[mf][r] + red[m * 68 + wn * 16 + lr];
            }
    }
}

__global__ __launch_bounds__(256) void k_e_bf(const u16* __restrict__ Pbf,
                                              const float* __restrict__ hWp,
                                              const float* __restrict__ w2,
                                              float* __restrict__ e) {
    int b = blockIdx.x, tg = blockIdx.y;
    __shared__ float hw[DHH];
    __shared__ float w2s[DHH];
    int tid = threadIdx.x;
    {
        float4 s = {0.f, 0.f, 0.f, 0.f};
#pragma unroll
        for (int ks = 0; ks < 8; ++ks) {
            float4 v = *(const float4*)&hWp[(size_t)(ks * 64 + b) * DHH + tid * 4];
            s.x += v.x; s.y += v.y; s.z += v.z; s.w += v.w;
        }
        *(float4*)&hw[tid * 4] = s;
        *(float4*)&w2s[tid * 4] = *(const float4*)&w2[tid * 4];
    }
    __syncthreads();
    int wave = tid >> 6, lane = tid & 63;
    const u16* Pb = Pbf + (size_t)b * TENC * DHH;
    for (int tt = 0; tt < 8; ++tt) {
        int t = tg * 32 + wave * 8 + tt;
        const u16* Pr = Pb + (size_t)t * DHH;
        float s = 0.f;
#pragma unroll
        for (int i = 0; i < 16; ++i) {
            int d = i * 64 + lane;
            s += tanh_fast(bf2f(Pr[d]) + hw[d]) * w2s[d];
        }
#pragma unroll
        for (int off = 32; off > 0; off >>= 1) s += __shfl_down(s, off);
        if (lane == 0) e[b * TENC + t] = s;
    }
}

__global__ __launch_bounds__(256) void k_sc2(const float* __restrict__ e,
                                             const float* __restrict__ enc,
                                             u16* __restrict__ xh,
                                             u16* __restrict__ xl) {
    int b = blockIdx.x, dq = blockIdx.y;
    __shared__ float al[TENC];
    __shared__ float red[256];
    __shared__ float4 pr[4][64];
    int tid = threadIdx.x;
    float v = (tid < TENC) ? e[b * TENC + tid] : -3.0e38f;
    red[tid] = v;
    __syncthreads();
    for (int s = 128; s > 0; s >>= 1) {
        if (tid < s) red[tid] = fmaxf(red[tid], red[tid + s]);
        __syncthreads();
    }
    float mx = red[0];
    __syncthreads();
    float ex = (tid < TENC) ? __expf(v - mx) : 0.f;
    red[tid] = ex;
    __syncthreads();
    for (int s = 128; s > 0; s >>= 1) {
        if (tid < s) red[tid] += red[tid + s];
        __syncthreads();
    }
    float inv = 1.f / red[0];
    if (tid < TENC) al[tid] = ex * inv;
    __syncthreads();
    int w = tid >> 6, l = tid & 63;
    int dbase = dq * 256 + l * 4;
    const float* ep = enc + ((size_t)b * TENC + w * 32) * DHH + dbase;
    float4 acc = {0.f, 0.f, 0.f, 0.f};
#pragma unroll 8
    for (int tt = 0; tt < 32; ++tt) {
        float a = al[w * 32 + tt];
        float4 vv = *(const float4*)(ep + (size_t)tt * DHH);
        acc.x += a * vv.x; acc.y += a * vv.y; acc.z += a * vv.z; acc.w += a * vv.w;
    }
    pr[w][l] = acc;
    __syncthreads();
    if (tid < 64) {
        float4 a0 = pr[0][tid], a1 = pr[1][tid], a2 = pr[2][tid], a3 = pr[3][tid];
        float r0 = a0.x + a1.x + a2.x + a3.x;
        float r1 = a0.y + a1.y + a2.y + a3.y;
        float r2 = a0.z + a1.z + a2.z + a3.z;
        float r3 = a0.w + a1.w + a2.w + a3.w;
        size_t o = (size_t)b * KTOT + dq * 256 + tid * 4;
        u16 h0 = f2bf(r0), h1 = f2bf(r1), h2 = f2bf(r2), h3 = f2bf(r3);
        ushort4 hv = {h0, h1, h2, h3};
        ushort4 lv = {f2bf(r0 - bf2f(h0)), f2bf(r1 - bf2f(h1)),
                      f2bf(r2 - bf2f(h2)), f2bf(r3 - bf2f(h3))};
        *(ushort4*)&xh[o] = hv;
        *(ushort4*)&xl[o] = lv;
    }
}

template <int SEG>
__global__ __launch_bounds__(512) void k_mma3(const u16* __restrict__ xh,
                                              const u16* __restrict__ xl,
                                              const u16* __restrict__ Wh,
                                              const u16* __restrict__ Wl,
                                              float* __restrict__ part) {
    __shared__ float red[64 * 68];
    int n0 = blockIdx.x * 64;
    int kseg = blockIdx.y;
    int tid = threadIdx.x;
    int wv = tid >> 6, l = tid & 63;
    int wn = wv & 3, kh = wv >> 2;
    int lr = l & 15, lk = (l >> 4) * 8;
    int n = n0 + wn * 16 + lr;
    const u16* wph = Wh + (size_t)n * KTOT + lk;
    const u16* wpl = Wl + (size_t)n * KTOT + lk;
    const u16* aph = xh + (size_t)lr * KTOT + lk;
    const u16* apl = xl + (size_t)lr * KTOT + lk;
    f32x4 z = {0.f, 0.f, 0.f, 0.f};
    f32x4 acc[4] = {z, z, z, z};
    const int KSEG = KTOT / SEG;
    const int KH = KSEG / 2;
    int kbeg = kseg * KSEG + kh * KH;
    for (int k = kbeg; k < kbeg + KH; k += 32) {
        bf16x8 bh = *(const bf16x8*)(wph + k);
        bf16x8 bl = *(const bf16x8*)(wpl + k);
#pragma unroll
        for (int mf = 0; mf < 4; ++mf) {
            size_t ao = (size_t)mf * 16 * KTOT + k;
            bf16x8 ah = *(const bf16x8*)(aph + ao);
            bf16x8 al = *(const bf16x8*)(apl + ao);
            acc[mf] = __builtin_amdgcn_mfma_f32_16x16x32_bf16(ah, bh, acc[mf], 0, 0, 0);
            acc[mf] = __builtin_amdgcn_mfma_f32_16x16x32_bf16(ah, bl, acc[mf], 0, 0, 0);
            acc[mf] = __builtin_amdgcn_mfma_f32_16x16x32_bf16(al, bh, acc[mf], 0, 0, 0);
        }
    }
    int moff = (l >> 4) * 4;
    if (kh == 0) {
#pragma unroll
        for (int mf = 0; mf < 4; ++mf)
#pragma unroll
            for (int r = 0; r < 4; ++r)
                red[(mf * 16 + moff + r) * 68 + wn * 16 + lr] = acc[mf][r];
    }
    __syncthreads();
    if (kh == 1) {
        float* dst = part + (size_t)kseg * 64 * GG;
#pragma unroll
        for (int mf = 0; mf < 4; ++mf)
#pragma unroll
            for (int r = 0; r < 4; ++r) {
                int m = mf * 16 + moff + r;
                dst[(size_t)m * GG + n] = acc[mf][r] + red[m * 68 + wn * 16 + lr];
            }
    }
}

__global__ __launch_bounds__(256) void k_pw2(const float* __restrict__ part, int nseg,
                                             const float* __restrict__ bih,
                                             const float* __restrict__ bhh,
                                             u16* __restrict__ xh,
                                             u16* __restrict__ xl,
                                             float* __restrict__ c,
                                             float* __restrict__ out, int t) {
    int b = blockIdx.x;
    __shared__ float g[GG];
    __shared__ float cs1[NCHN], cs2[NCHN], t1[NCHN], t2[NCHN];
    int tid = threadIdx.x;
    for (int p = 0; p < 34; ++p) {
        int j = p * 256 + tid;
        float s = bih[j] + bhh[j];
        for (int ks = 0; ks < nseg; ++ks) s += part[(size_t)(ks * 64 + b) * GG + j];
        g[j] = s;
    }
    __syncthreads();
    float x1 = g[tid], x2 = g[NCHN + tid];
    t1[tid] = x1; t2[tid] = x2;
    __syncthreads();
    for (int s = 128; s > 0; s >>= 1) {
        if (tid < s) { t1[tid] = fmaxf(t1[tid], t1[tid + s]); t2[tid] = fmaxf(t2[tid], t2[tid + s]); }
        __syncthreads();
    }
    float m1 = t1[0], m2 = t2[0];
    __syncthreads();
    float e1 = __expf(x1 - m1), e2 = __expf(x2 - m2);
    t1[tid] = e1; t2[tid] = e2;
    __syncthreads();
    for (int s = 128; s > 0; s >>= 1) {
        if (tid < s) { t1[tid] += t1[tid + s]; t2[tid] += t2[tid + s]; }
        __syncthreads();
    }
    float inv1 = 1.f / t1[0], inv2 = 1.f / t2[0];
    __syncthreads();
    cs1[tid] = e1; cs2[tid] = e2;
    __syncthreads();
    for (int off = 1; off < NCHN; off <<= 1) {
        float a1 = (tid >= off) ? cs1[tid - off] : 0.f;
        float a2 = (tid >= off) ? cs2[tid - off] : 0.f;
        __syncthreads();
        cs1[tid] += a1; cs2[tid] += a2;
        __syncthreads();
    }
    float* cb = c + (size_t)b * DVV;
    float* ob = out + ((size_t)b * TDEC + t) * DVV;
    u16* xhb = xh + (size_t)b * KTOT + 1024;
    u16* xlb = xl + (size_t)b * KTOT + 1024;
    for (int p = 0; p < 8; ++p) {
        int idx = p * 256 + tid;
        int ch = idx >> 3;
        float cin = 1.f - cs1[ch] * inv1;
        float cfg = cs2[ch] * inv2;
        float ov = cfg * cin;
        float oo = sigmoid_fast(g[512 + idx]);
        float gg = tanh_fast(g[2560 + idx]);
        float ii = sigmoid_fast(g[4608 + idx]);
        float ff = sigmoid_fast(g[6656 + idx]);
        float fg = ff * ov + (cfg - ov);
        float ig = ii * ov + (cin - ov);
        float cy = fg * cb[idx] + ig * gg;
        cb[idx] = cy;
        float hy = oo * tanh_fast(cy);
        ob[idx] = hy;
        u16 hh = f2bf(hy);
        xhb[idx] = hh;
        xlb[idx] = f2bf(hy - bf2f(hh));
    }
}

// ===================== launch =====================

extern "C" void kernel_launch(void* const* d_in, const int* in_sizes, int n_in,
                              void* d_out, int out_size, void* d_ws, size_t ws_size,
                              hipStream_t stream) {
    const float* enc    = (const float*)d_in[0];
    const float* W_att1 = (const float*)d_in[2];
    const float* b_att1 = (const float*)d_in[3];
    const float* w_att2 = (const float*)d_in[4];
    const float* W_ih   = (const float*)d_in[5];
    const float* b_ih   = (const float*)d_in[6];
    const float* W_hh   = (const float*)d_in[7];
    const float* b_hh   = (const float*)d_in[8];
    float* out = (float*)d_out;
    float* ws  = (float*)d_ws;
    const float* Wh_att = W_att1 + 1024 * 1024;

    // layout (151,323,648 B total)
    float* hWp  = ws;                          // 16*64*1024 = 1,048,576 f
    float* ebuf = hWp + 1048576;               // 8,192 f
    float* gp   = ebuf + 8192;                 // 8*64*8704 = 4,456,448 f
    float* c    = gp + 4456448;                // 131,072 f
    int*   bar  = (int*)(c + 131072);          // 8,448 ints (flags + gen)
    u16* Pbf = (u16*)(bar + 8448);             // 8,388,608
    u16* xh  = Pbf + 8388608;                  // 196,608
    u16* xl  = xh + 196608;                    // 196,608
    u16* Wth = xl + 196608;                    // 26,738,688
    u16* Wtl = Wth + 26738688;                 // 26,738,688
    u16* Wta = Wtl + 26738688;                 // 2,097,152
    if (ws_size < 151323648ull) return;

    // precompute (one-time per call)
    k_cvt<true><<<dim3(136, 48), 256, 0, stream>>>(W_ih, W_hh, 1024, GG, KTOT, Wth, Wtl);
    k_cvt<false><<<dim3(16, 32), 256, 0, stream>>>(Wh_att, Wh_att, 2048, DHH, 2048, Wta, Wta);
    k_Pb<<<dim3(16, 128), 256, 0, stream>>>(enc, W_att1, b_att1, Pbf);
    k_init2<<<768, 256, 0, stream>>>(c, xh, xl, bar);

    // persistent cooperative decode
    void* args[] = {(void*)&Pbf, (void*)&hWp, (void*)&ebuf, (void*)&gp, (void*)&c,
                    (void*)&xh, (void*)&xl, (void*)&Wth, (void*)&Wtl, (void*)&Wta,
                    (void*)&enc, (void*)&w_att2, (void*)&b_ih, (void*)&b_hh,
                    (void*)&out, (void*)&bar};
    hipError_t err = hipLaunchCooperativeKernel((const void*)k_decode,
                                                dim3(256), dim3(512), args, 0, stream);
    if (err != hipSuccess) {
        (void)hipGetLastError();
        // fallback: multi-kernel loop (correct, slower)
        for (int t = 0; t < TDEC; ++t) {
            k_mma1<<<dim3(16, 8), 512, 0, stream>>>(xh, Wta, hWp);
            k_e_bf<<<dim3(BB, 4), 256, 0, stream>>>(Pbf, hWp, w_att2, ebuf);
            k_sc2<<<dim3(BB, 4), 256, 0, stream>>>(ebuf, enc, xh, xl);
            k_mma3<4><<<dim3(136, 4), 512, 0, stream>>>(xh, xl, Wth, Wtl, gp);
            k_pw2<<<BB, 256, 0, stream>>>(gp, 4, b_ih, b_hh, xh, xl, c, out, t);
        }
    }
}

// Round 7
// 13160.085 us; speedup vs baseline: 4.5832x; 1.9067x over previous
//
#include <hip/hip_runtime.h>
#include <math.h>

#define BB   64
#define TENC 128
#define TDEC 64
#define DHH  1024
#define DVV  2048
#define NCHN 256
#define GG   8704   // 4*DV + 2*NCH
#define KTOT 3072   // DH + DV

typedef unsigned short u16;
typedef unsigned int   u32;
typedef unsigned long long u64;
typedef __bf16 bf16x8 __attribute__((ext_vector_type(8)));
typedef float  f32x4  __attribute__((ext_vector_type(4)));

__device__ __forceinline__ u16 f2bf(float f) {
    unsigned u = __float_as_uint(f);
    unsigned r = (u + 0x7fffu + ((u >> 16) & 1u)) >> 16;
    return (u16)r;
}
__device__ __forceinline__ float bf2f(u16 s) { return __uint_as_float(((unsigned)s) << 16); }
__device__ __forceinline__ float tanh_fast(float x) {
    float xc = fminf(fmaxf(x, -15.f), 15.f);
    float t = __expf(2.f * xc);
    return 1.f - 2.f * __builtin_amdgcn_rcpf(t + 1.f);
}
__device__ __forceinline__ float sigmoid_fast(float x) {
    float xc = fminf(fmaxf(x, -30.f), 30.f);
    return __builtin_amdgcn_rcpf(1.f + __expf(-xc));
}

// ---- sc1 (agent-scope, L2-bypassing) relaxed accessors: no fences ever ----
__device__ __forceinline__ float ldf(const float* p) {
    return __uint_as_float(__hip_atomic_load((u32*)p, __ATOMIC_RELAXED, __HIP_MEMORY_SCOPE_AGENT));
}
__device__ __forceinline__ void stf(float* p, float v) {
    __hip_atomic_store((u32*)p, __float_as_uint(v), __ATOMIC_RELAXED, __HIP_MEMORY_SCOPE_AGENT);
}
__device__ __forceinline__ u64 ld8(const u16* p) {
    return __hip_atomic_load((u64*)p, __ATOMIC_RELAXED, __HIP_MEMORY_SCOPE_AGENT);
}
__device__ __forceinline__ void st4(u16* p, u32 v) {
    __hip_atomic_store((u32*)p, v, __ATOMIC_RELAXED, __HIP_MEMORY_SCOPE_AGENT);
}

// ---- zero-fence grid barrier ----
// All cross-block data travels via sc1 (fabric/MALL) -> no cache maintenance
// needed. __syncthreads() drains each wave's vmcnt before s_barrier, so all
// sc1 stores are globally visible before the flag is raised.
// 8 gen cachelines de-contend the broadcast (32 pollers per line).
__device__ __forceinline__ void gbar(int* flags, int* gens, int target) {
    __syncthreads();
    int tid = threadIdx.x;
    if (blockIdx.x == 0) {
        if (tid > 0 && tid < 256) {
            while (__hip_atomic_load(flags + tid * 32, __ATOMIC_RELAXED,
                                     __HIP_MEMORY_SCOPE_AGENT) < target)
                __builtin_amdgcn_s_sleep(2);
        }
        __syncthreads();
        if (tid < 8)
            __hip_atomic_store(gens + tid * 32, target, __ATOMIC_RELAXED,
                               __HIP_MEMORY_SCOPE_AGENT);
    } else {
        if (tid == 0) {
            __hip_atomic_store(flags + blockIdx.x * 32, target, __ATOMIC_RELAXED,
                               __HIP_MEMORY_SCOPE_AGENT);
            while (__hip_atomic_load(gens + (blockIdx.x & 7) * 32, __ATOMIC_RELAXED,
                                     __HIP_MEMORY_SCOPE_AGENT) < target)
                __builtin_amdgcn_s_sleep(2);
        }
        __syncthreads();
    }
}

// ===================== precompute kernels =====================

__global__ __launch_bounds__(256) void k_init2(float* c, u16* xh, u16* xl, int* bar) {
    int i = blockIdx.x * 256 + threadIdx.x;   // grid 768 -> 196608
    xh[i] = 0; xl[i] = 0;
    if (i < BB * DVV) c[i] = 0.f;
    if (i < 8448) bar[i] = 0;
}

template <bool LO>
__global__ __launch_bounds__(256) void k_cvt(const float* __restrict__ S1,
                                             const float* __restrict__ S2,
                                             int K1, int N, int K,
                                             u16* __restrict__ Dh,
                                             u16* __restrict__ Dl) {
    __shared__ float t[64][65];
    int n0 = blockIdx.x * 64, k0 = blockIdx.y * 64;
    int tid = threadIdx.x;
    int cn = tid & 63, r4 = tid >> 6;
#pragma unroll
    for (int p = 0; p < 16; ++p) {
        int kk = p * 4 + r4;
        int kg = k0 + kk;
        const float* src = (kg < K1) ? S1 + (size_t)kg * N : S2 + (size_t)(kg - K1) * N;
        t[kk][cn] = src[n0 + cn];
    }
    __syncthreads();
    int ck = tid & 63, n4 = tid >> 6;
#pragma unroll
    for (int p = 0; p < 16; ++p) {
        int nn = p * 4 + n4;
        float w = t[ck][nn];
        u16 hi = f2bf(w);
        size_t o = (size_t)(n0 + nn) * K + k0 + ck;
        Dh[o] = hi;
        if (LO) Dl[o] = f2bf(w - bf2f(hi));
    }
}

__global__ __launch_bounds__(256) void k_Pb(const float* __restrict__ enc,
                                            const float* __restrict__ W1,
                                            const float* __restrict__ b1,
                                            u16* __restrict__ Pb) {
    __shared__ float As[32][68];
    __shared__ float Bs[32][68];
    int j0 = blockIdx.x * 64;
    int m0 = blockIdx.y * 64;
    int tid = threadIdx.x;
    int jg = tid & 15, bg = tid >> 4;
    float acc[4][4] = {};
    for (int k0 = 0; k0 < DHH; k0 += 32) {
#pragma unroll
        for (int p = 0; p < 8; ++p) {
            int r = p * 8 + (tid >> 5);
            int kk = tid & 31;
            As[kk][r] = enc[(size_t)(m0 + r) * DHH + k0 + kk];
        }
#pragma unroll
        for (int p = 0; p < 8; ++p) {
            int kk = p * 4 + (tid >> 6);
            int jl = tid & 63;
            Bs[kk][jl] = W1[(size_t)(k0 + kk) * DHH + j0 + jl];
        }
        __syncthreads();
#pragma unroll
        for (int kk = 0; kk < 32; ++kk) {
            float4 a = *(const float4*)&As[kk][bg * 4];
            float4 b = *(const float4*)&Bs[kk][jg * 4];
            float av[4] = {a.x, a.y, a.z, a.w};
            float bv[4] = {b.x, b.y, b.z, b.w};
#pragma unroll
            for (int i = 0; i < 4; ++i)
#pragma unroll
                for (int j = 0; j < 4; ++j) acc[i][j] += av[i] * bv[j];
        }
        __syncthreads();
    }
    float4 bb = *(const float4*)&b1[j0 + jg * 4];
    float bia[4] = {bb.x, bb.y, bb.z, bb.w};
#pragma unroll
    for (int i = 0; i < 4; ++i) {
        int r = m0 + bg * 4 + i;
        ushort4 sv;
        sv.x = f2bf(acc[i][0] + bia[0]);
        sv.y = f2bf(acc[i][1] + bia[1]);
        sv.z = f2bf(acc[i][2] + bia[2]);
        sv.w = f2bf(acc[i][3] + bia[3]);
        *(ushort4*)&Pb[(size_t)r * DHH + j0 + jg * 4] = sv;
    }
}

// ===================== persistent decode kernel =====================
// Cached (never invalidated): Wth/Wtl/Wta, Pbf, enc, w2, bih, bhh, c(block-local), out.
// sc1 (fabric): hWp, xh/xl, gp, flags/gens.
// 4 flag-only barriers/step: A (hW) | BC (attn) | D (gates) | E (pointwise)

__global__ __launch_bounds__(512) void k_decode(
        const u16* Pbf, float* hWp, float* gp, float* c,
        u16* xh, u16* xl,
        const u16* __restrict__ Wth, const u16* __restrict__ Wtl,
        const u16* __restrict__ Wta,
        const float* __restrict__ enc, const float* __restrict__ w2,
        const float* __restrict__ bih, const float* __restrict__ bhh,
        float* out, int* bar) {
    __shared__ u64 smem8[13312];   // 106,496 B, reused per phase
    float* smf = (float*)smem8;
    int* flags = bar;
    int* gens = bar + 8192;
    int blk = blockIdx.x, tid = threadIdx.x;
    int wv = tid >> 6, l = tid & 63;
    int lr = l & 15, lk4 = l >> 4;
    f32x4 z = {0.f, 0.f, 0.f, 0.f};
    int bt = 1;

    for (int t = 0; t < TDEC; ++t) {
        // ---------- phase A: hW partials (16 n-tiles x 16 ksegs of 128) ----------
        {
            int nt = blk & 15, kseg = blk >> 4;
            int wn = wv & 3, kh = wv >> 2;
            // stage x h-slice [64 rows x 128 cols hi] -> LDS, row pitch 20 units(320B)
            u16* lsa = (u16*)smem8;
            for (int u = tid; u < 1024; u += 512) {
                int row = u >> 4, cu = u & 15;
                const u16* gs = xh + (size_t)row * KTOT + 1024 + kseg * 128 + cu * 8;
                u64 a0 = ld8(gs), a1 = ld8(gs + 4);
                u16* d = lsa + (((row * 20 + cu)) << 3);
                *(u64*)d = a0; *(u64*)(d + 4) = a1;
            }
            __syncthreads();
            int n = nt * 64 + wn * 16 + lr;
            const u16* wp = Wta + (size_t)n * 2048 + kseg * 128 + kh * 64 + lk4 * 8;
            f32x4 acc[4] = {z, z, z, z};
#pragma unroll
            for (int kk = 0; kk < 64; kk += 32) {
                bf16x8 bfrag = *(const bf16x8*)(wp + kk);
#pragma unroll
                for (int mf = 0; mf < 4; ++mf) {
                    int row = mf * 16 + lr;
                    int unit = kh * 8 + lk4 + (kk >> 3);
                    bf16x8 a = *(const bf16x8*)(lsa + ((row * 20 + unit) << 3));
                    acc[mf] = __builtin_amdgcn_mfma_f32_16x16x32_bf16(a, bfrag, acc[mf], 0, 0, 0);
                }
            }
            float* red = (float*)((char*)smem8 + 20480);   // 64 x 68
            if (kh == 0) {
#pragma unroll
                for (int mf = 0; mf < 4; ++mf)
#pragma unroll
                    for (int r = 0; r < 4; ++r)
                        red[(mf * 16 + lk4 * 4 + r) * 68 + wn * 16 + lr] = acc[mf][r];
            }
            __syncthreads();
            if (kh == 1) {
#pragma unroll
                for (int mf = 0; mf < 4; ++mf)
#pragma unroll
                    for (int r = 0; r < 4; ++r) {
                        int m = mf * 16 + lk4 * 4 + r;
                        stf(&hWp[(size_t)(kseg * 64 + m) * DHH + n],
                            acc[mf][r] + red[m * 68 + wn * 16 + lr]);
                    }
            }
        }
        gbar(flags, gens, bt++);

        // ---------- phase BC (blocks 0..63 = batch b): e, softmax, context ----------
        if (blk < BB) {
            int b = blk;
            float* hw  = smf;             // 1024
            float* w2s = smf + 1024;      // 1024
            float* er  = smf + 2048;      // 128
            float* al  = smf + 2176;      // 128
            float* red = smf + 2304;      // 512
            float* pr  = smf + 2816;      // 8192
#pragma unroll
            for (int p = 0; p < 2; ++p) {
                int d = p * 512 + tid;
                float s = 0.f;
#pragma unroll
                for (int ks = 0; ks < 16; ++ks) s += ldf(&hWp[(size_t)(ks * 64 + b) * DHH + d]);
                hw[d] = s;
                w2s[d] = w2[d];
            }
            __syncthreads();
            const u16* Pb = Pbf + (size_t)b * TENC * DHH;
#pragma unroll
            for (int i = 0; i < 16; ++i) {
                int tt = wv * 16 + i;
                const u16* Pr = Pb + (size_t)tt * DHH;
                float s = 0.f;
#pragma unroll
                for (int q = 0; q < 16; ++q) {
                    int d = q * 64 + l;
                    s += tanh_fast(bf2f(Pr[d]) + hw[d]) * w2s[d];
                }
#pragma unroll
                for (int off = 32; off > 0; off >>= 1) s += __shfl_down(s, off);
                if (l == 0) er[tt] = s;
            }
            __syncthreads();
            float v = (tid < TENC) ? er[tid] : -3.0e38f;
            red[tid] = v;
            __syncthreads();
            for (int s = 256; s > 0; s >>= 1) {
                if (tid < s) red[tid] = fmaxf(red[tid], red[tid + s]);
                __syncthreads();
            }
            float mx = red[0];
            __syncthreads();
            float ex = (tid < TENC) ? __expf(v - mx) : 0.f;
            red[tid] = ex;
            __syncthreads();
            for (int s = 256; s > 0; s >>= 1) {
                if (tid < s) red[tid] += red[tid + s];
                __syncthreads();
            }
            float inv = 1.f / red[0];
            if (tid < TENC) al[tid] = ex * inv;
            __syncthreads();
            float acc[16];
#pragma unroll
            for (int j = 0; j < 16; ++j) acc[j] = 0.f;
            const float* eb = enc + (size_t)b * TENC * DHH;
            for (int i = 0; i < 16; ++i) {
                int tt = wv * 16 + i;
                float a = al[tt];
                const float* row = eb + (size_t)tt * DHH;
#pragma unroll
                for (int j = 0; j < 16; ++j) acc[j] += a * row[j * 64 + l];
            }
#pragma unroll
            for (int j = 0; j < 16; ++j) pr[wv * 1024 + j * 64 + l] = acc[j];
            __syncthreads();
            {
                int d0 = tid * 2;
                float s0 = 0.f, s1 = 0.f;
#pragma unroll
                for (int w = 0; w < 8; ++w) { s0 += pr[w * 1024 + d0]; s1 += pr[w * 1024 + d0 + 1]; }
                u16 h0 = f2bf(s0), h1 = f2bf(s1);
                u16 l0 = f2bf(s0 - bf2f(h0)), l1 = f2bf(s1 - bf2f(h1));
                st4(xh + (size_t)b * KTOT + d0, (u32)h0 | ((u32)h1 << 16));
                st4(xl + (size_t)b * KTOT + d0, (u32)l0 | ((u32)l1 << 16));
            }
        }
        gbar(flags, gens, bt++);

        // ---------- phase D: gates partials. block = (kq of 8, group of 32) ----------
        {
            int kq = blk & 7, g = blk >> 3;
            // stage x slice [64 rows x 384 cols, hi+lo] -> LDS, row pitch 52 units(832B)
            u16* lh = (u16*)smem8;
            u16* ll = lh + 64 * 52 * 8;
            for (int u = tid; u < 3072; u += 512) {
                int row = u / 48, cu = u - row * 48;
                size_t gb = (size_t)row * KTOT + kq * 384 + cu * 8;
                u64 a0 = ld8(xh + gb), a1 = ld8(xh + gb + 4);
                u64 b0 = ld8(xl + gb), b1 = ld8(xl + gb + 4);
                u16* dh = lh + ((row * 52 + cu) << 3);
                u16* dl = ll + ((row * 52 + cu) << 3);
                *(u64*)dh = a0; *(u64*)(dh + 4) = a1;
                *(u64*)dl = b0; *(u64*)(dl + 4) = b1;
            }
            __syncthreads();
            int t0 = (272 * g) >> 5, t1 = (272 * (g + 1)) >> 5;
            for (int nt = t0 + wv; nt < t1; nt += 8) {
                int n0 = nt * 32 + lr;
                const u16* wph0 = Wth + (size_t)n0 * KTOT + kq * 384 + lk4 * 8;
                const u16* wpl0 = Wtl + (size_t)n0 * KTOT + kq * 384 + lk4 * 8;
                const u16* wph1 = wph0 + (size_t)16 * KTOT;
                const u16* wpl1 = wpl0 + (size_t)16 * KTOT;
                f32x4 acc0[4] = {z, z, z, z};
                f32x4 acc1[4] = {z, z, z, z};
                for (int kk = 0; kk < 384; kk += 32) {
                    bf16x8 bh0 = *(const bf16x8*)(wph0 + kk);
                    bf16x8 bl0 = *(const bf16x8*)(wpl0 + kk);
                    bf16x8 bh1 = *(const bf16x8*)(wph1 + kk);
                    bf16x8 bl1 = *(const bf16x8*)(wpl1 + kk);
                    int ub = (kk >> 3) + lk4;
#pragma unroll
                    for (int mf = 0; mf < 4; ++mf) {
                        int row = mf * 16 + lr;
                        bf16x8 ah = *(const bf16x8*)(lh + ((row * 52 + ub) << 3));
                        bf16x8 al_ = *(const bf16x8*)(ll + ((row * 52 + ub) << 3));
                        acc0[mf] = __builtin_amdgcn_mfma_f32_16x16x32_bf16(ah, bh0, acc0[mf], 0, 0, 0);
                        acc0[mf] = __builtin_amdgcn_mfma_f32_16x16x32_bf16(ah, bl0, acc0[mf], 0, 0, 0);
                        acc0[mf] = __builtin_amdgcn_mfma_f32_16x16x32_bf16(al_, bh0, acc0[mf], 0, 0, 0);
                        acc1[mf] = __builtin_amdgcn_mfma_f32_16x16x32_bf16(ah, bh1, acc1[mf], 0, 0, 0);
                        acc1[mf] = __builtin_amdgcn_mfma_f32_16x16x32_bf16(ah, bl1, acc1[mf], 0, 0, 0);
                        acc1[mf] = __builtin_amdgcn_mfma_f32_16x16x32_bf16(al_, bh1, acc1[mf], 0, 0, 0);
                    }
                }
                float* dst = gp + (size_t)kq * 64 * GG;
#pragma unroll
                for (int mf = 0; mf < 4; ++mf)
#pragma unroll
                    for (int r = 0; r < 4; ++r) {
                        int m = mf * 16 + lk4 * 4 + r;
                        stf(&dst[(size_t)m * GG + nt * 32 + lr], acc0[mf][r]);
                        stf(&dst[(size_t)m * GG + nt * 32 + 16 + lr], acc1[mf][r]);
                    }
            }
        }
        gbar(flags, gens, bt++);

        // ---------- phase E: gate reduce + cumsoftmax + ON-LSTM (64b x 4q) ----------
        {
            int b = blk >> 2, q = blk & 3;
            float* g0 = smf;                  // 512
            float* gq = smf + 512;            // 2048
            float* cs1 = smf + 2560;          // 256
            float* cs2 = cs1 + 256;
            float* r1 = cs2 + 256;
            float* r2 = r1 + 256;
            {
                int j = tid;
                float s = bih[j] + bhh[j];
#pragma unroll
                for (int ks = 0; ks < 8; ++ks) s += ldf(&gp[(size_t)(ks * 64 + b) * GG + j]);
                g0[j] = s;
            }
#pragma unroll
            for (int sec = 0; sec < 4; ++sec) {
                int j = 512 + sec * 2048 + q * 512 + tid;
                float s = bih[j] + bhh[j];
#pragma unroll
                for (int ks = 0; ks < 8; ++ks) s += ldf(&gp[(size_t)(ks * 64 + b) * GG + j]);
                gq[sec * 512 + tid] = s;
            }
            __syncthreads();
            float x1 = 0.f, x2 = 0.f;
            if (tid < 256) { x1 = g0[tid]; x2 = g0[NCHN + tid]; r1[tid] = x1; r2[tid] = x2; }
            __syncthreads();
            for (int s = 128; s > 0; s >>= 1) {
                if (tid < s) { r1[tid] = fmaxf(r1[tid], r1[tid + s]); r2[tid] = fmaxf(r2[tid], r2[tid + s]); }
                __syncthreads();
            }
            float m1 = r1[0], m2 = r2[0];
            __syncthreads();
            float e1 = 0.f, e2 = 0.f;
            if (tid < 256) {
                e1 = __expf(x1 - m1); e2 = __expf(x2 - m2);
                r1[tid] = e1; r2[tid] = e2; cs1[tid] = e1; cs2[tid] = e2;
            }
            __syncthreads();
            for (int s = 128; s > 0; s >>= 1) {
                if (tid < s) { r1[tid] += r1[tid + s]; r2[tid] += r2[tid + s]; }
                __syncthreads();
            }
            float inv1 = 1.f / r1[0], inv2 = 1.f / r2[0];
            __syncthreads();
            for (int off = 1; off < NCHN; off <<= 1) {
                float a1 = 0.f, a2 = 0.f;
                if (tid < NCHN && tid >= off) { a1 = cs1[tid - off]; a2 = cs2[tid - off]; }
                __syncthreads();
                if (tid < NCHN) { cs1[tid] += a1; cs2[tid] += a2; }
                __syncthreads();
            }
            float* cb = c + (size_t)b * DVV;
            float* ob = out + ((size_t)b * TDEC + t) * DVV;
            u16* xhb = xh + (size_t)b * KTOT + 1024;
            u16* xlb = xl + (size_t)b * KTOT + 1024;
            if (tid < 256) {
                int i0 = 2 * tid;
                int idx = q * 512 + i0;
                u16 hh[2], lll[2];
#pragma unroll
                for (int e = 0; e < 2; ++e) {
                    int i = i0 + e;
                    int ch = (q * 512 + i) >> 3;
                    float cin = 1.f - cs1[ch] * inv1;
                    float cfg = cs2[ch] * inv2;
                    float ov = cfg * cin;
                    float oo = sigmoid_fast(gq[i]);
                    float gg = tanh_fast(gq[512 + i]);
                    float ii = sigmoid_fast(gq[1024 + i]);
                    float ff = sigmoid_fast(gq[1536 + i]);
                    float fg = ff * ov + (cfg - ov);
                    float ig = ii * ov + (cin - ov);
                    float cy = fg * cb[idx + e] + ig * gg;
                    cb[idx + e] = cy;
                    float hy = oo * tanh_fast(cy);
                    ob[idx + e] = hy;
                    hh[e] = f2bf(hy);
                    lll[e] = f2bf(hy - bf2f(hh[e]));
                }
                st4(xhb + idx, (u32)hh[0] | ((u32)hh[1] << 16));
                st4(xlb + idx, (u32)lll[0] | ((u32)lll[1] << 16));
            }
        }
        gbar(flags, gens, bt++);
    }
}

// ===================== fallback multi-kernel path =====================

__global__ __launch_bounds__(512) void k_mma1(const u16* __restrict__ xh,
                                              const u16* __restrict__ Wta,
                                              float* __restrict__ hWp) {
    __shared__ float red[64 * 68];
    int n0 = blockIdx.x * 64;
    int kseg = blockIdx.y;
    int tid = threadIdx.x;
    int wv = tid >> 6, l = tid & 63;
    int wn = wv & 3, kh = wv >> 2;
    int lr = l & 15, lk = (l >> 4) * 8;
    int n = n0 + wn * 16 + lr;
    const u16* wp = Wta + (size_t)n * 2048 + lk;
    const u16* ap = xh + (size_t)lr * KTOT + 1024 + lk;
    f32x4 z = {0.f, 0.f, 0.f, 0.f};
    f32x4 acc[4] = {z, z, z, z};
    int kbeg = kseg * 256 + kh * 128;
    for (int k = kbeg; k < kbeg + 128; k += 32) {
        bf16x8 bfrag = *(const bf16x8*)(wp + k);
#pragma unroll
        for (int mf = 0; mf < 4; ++mf) {
            bf16x8 a = *(const bf16x8*)(ap + (size_t)mf * 16 * KTOT + k);
            acc[mf] = __builtin_amdgcn_mfma_f32_16x16x32_bf16(a, bfrag, acc[mf], 0, 0, 0);
        }
    }
    int moff = (l >> 4) * 4;
    if (kh == 0) {
#pragma unroll
        for (int mf = 0; mf < 4; ++mf)
#pragma unroll
            for (int r = 0; r < 4; ++r)
                red[(mf * 16 + moff + r) * 68 + wn * 16 + lr] = acc[mf][r];
    }
    __syncthreads();
    if (kh == 1) {
        float* dst = hWp + (size_t)(kseg * 2) * 64 * DHH;   // store as 2 of 16 segs
#pragma unroll
        for (int mf = 0; mf < 4; ++mf)
#pragma unroll
            for (int r = 0; r < 4; ++r) {
                int m = mf * 16 + moff + r;
                dst[(size_t)m * DHH + n] = acc[mf][r] + red[m * 68 + wn * 16 + lr];
                hWp[(size_t)((kseg * 2 + 1) * 64 + m) * DHH + n] = 0.f;
            }
    }
}

__global__ __launch_bounds__(256) void k_e_bf(const u16* __restrict__ Pbf,
                                              const float* __restrict__ hWp,
                                              const float* __restrict__ w2,
                                              float* __restrict__ e) {
    int b = blockIdx.x, tg = blockIdx.y;
    __shared__ float hw[DHH];
    __shared__ float w2s[DHH];
    int tid = threadIdx.x;
    {
        float4 s = {0.f, 0.f, 0.f, 0.f};
#pragma unroll
        for (int ks = 0; ks < 16; ++ks) {
            float4 v = *(const float4*)&hWp[(size_t)(ks * 64 + b) * DHH + tid * 4];
            s.x += v.x; s.y += v.y; s.z += v.z; s.w += v.w;
        }
        *(float4*)&hw[tid * 4] = s;
        *(float4*)&w2s[tid * 4] = *(const float4*)&w2[tid * 4];
    }
    __syncthreads();
    int wave = tid >> 6, lane = tid & 63;
    const u16* Pb = Pbf + (size_t)b * TENC * DHH;
    for (int tt = 0; tt < 8; ++tt) {
        int t = tg * 32 + wave * 8 + tt;
        const u16* Pr = Pb + (size_t)t * DHH;
        float s = 0.f;
#pragma unroll
        for (int i = 0; i < 16; ++i) {
            int d = i * 64 + lane;
            s += tanh_fast(bf2f(Pr[d]) + hw[d]) * w2s[d];
        }
#pragma unroll
        for (int off = 32; off > 0; off >>= 1) s += __shfl_down(s, off);
        if (lane == 0) e[b * TENC + t] = s;
    }
}

__global__ __launch_bounds__(256) void k_sc2(const float* __restrict__ e,
                                             const float* __restrict__ enc,
                                             u16* __restrict__ xh,
                                             u16* __restrict__ xl) {
    int b = blockIdx.x, dq = blockIdx.y;
    __shared__ float al[TENC];
    __shared__ float red[256];
    __shared__ float4 pr[4][64];
    int tid = threadIdx.x;
    float v = (tid < TENC) ? e[b * TENC + tid] : -3.0e38f;
    red[tid] = v;
    __syncthreads();
    for (int s = 128; s > 0; s >>= 1) {
        if (tid < s) red[tid] = fmaxf(red[tid], red[tid + s]);
        __syncthreads();
    }
    float mx = red[0];
    __syncthreads();
    float ex = (tid < TENC) ? __expf(v - mx) : 0.f;
    red[tid] = ex;
    __syncthreads();
    for (int s = 128; s > 0; s >>= 1) {
        if (tid < s) red[tid] += red[tid + s];
        __syncthreads();
    }
    float inv = 1.f / red[0];
    if (tid < TENC) al[tid] = ex * inv;
    __syncthreads();
    int w = tid >> 6, l = tid & 63;
    int dbase = dq * 256 + l * 4;
    const float* ep = enc + ((size_t)b * TENC + w * 32) * DHH + dbase;
    float4 acc = {0.f, 0.f, 0.f, 0.f};
#pragma unroll 8
    for (int tt = 0; tt < 32; ++tt) {
        float a = al[w * 32 + tt];
        float4 vv = *(const float4*)(ep + (size_t)tt * DHH);
        acc.x += a * vv.x; acc.y += a * vv.y; acc.z += a * vv.z; acc.w += a * vv.w;
    }
    pr[w][l] = acc;
    __syncthreads();
    if (tid < 64) {
        float4 a0 = pr[0][tid], a1 = pr[1][tid], a2 = pr[2][tid], a3 = pr[3][tid];
        float r0 = a0.x + a1.x + a2.x + a3.x;
        float r1 = a0.y + a1.y + a2.y + a3.y;
        float r2 = a0.z + a1.z + a2.z + a3.z;
        float r3 = a0.w + a1.w + a2.w + a3.w;
        size_t o = (size_t)b * KTOT + dq * 256 + tid * 4;
        u16 h0 = f2bf(r0), h1 = f2bf(r1), h2 = f2bf(r2), h3 = f2bf(r3);
        ushort4 hv = {h0, h1, h2, h3};
        ushort4 lv = {f2bf(r0 - bf2f(h0)), f2bf(r1 - bf2f(h1)),
                      f2bf(r2 - bf2f(h2)), f2bf(r3 - bf2f(h3))};
        *(ushort4*)&xh[o] = hv;
        *(ushort4*)&xl[o] = lv;
    }
}

template <int SEG>
__global__ __launch_bounds__(512) void k_mma3(const u16* __restrict__ xh,
                                              const u16* __restrict__ xl,
                                              const u16* __restrict__ Wh,
                                              const u16* __restrict__ Wl,
                                              float* __restrict__ part) {
    __shared__ float red[64 * 68];
    int n0 = blockIdx.x * 64;
    int kseg = blockIdx.y;
    int tid = threadIdx.x;
    int wv = tid >> 6, l = tid & 63;
    int wn = wv & 3, kh = wv >> 2;
    int lr = l & 15, lk = (l >> 4) * 8;
    int n = n0 + wn * 16 + lr;
    const u16* wph = Wh + (size_t)n * KTOT + lk;
    const u16* wpl = Wl + (size_t)n * KTOT + lk;
    const u16* aph = xh + (size_t)lr * KTOT + lk;
    const u16* apl = xl + (size_t)lr * KTOT + lk;
    f32x4 z = {0.f, 0.f, 0.f, 0.f};
    f32x4 acc[4] = {z, z, z, z};
    const int KSEG = KTOT / SEG;
    const int KH = KSEG / 2;
    int kbeg = kseg * KSEG + kh * KH;
    for (int k = kbeg; k < kbeg + KH; k += 32) {
        bf16x8 bh = *(const bf16x8*)(wph + k);
        bf16x8 bl = *(const bf16x8*)(wpl + k);
#pragma unroll
        for (int mf = 0; mf < 4; ++mf) {
            size_t ao = (size_t)mf * 16 * KTOT + k;
            bf16x8 ah = *(const bf16x8*)(aph + ao);
            bf16x8 al = *(const bf16x8*)(apl + ao);
            acc[mf] = __builtin_amdgcn_mfma_f32_16x16x32_bf16(ah, bh, acc[mf], 0, 0, 0);
            acc[mf] = __builtin_amdgcn_mfma_f32_16x16x32_bf16(ah, bl, acc[mf], 0, 0, 0);
            acc[mf] = __builtin_amdgcn_mfma_f32_16x16x32_bf16(al, bh, acc[mf], 0, 0, 0);
        }
    }
    int moff = (l >> 4) * 4;
    if (kh == 0) {
#pragma unroll
        for (int mf = 0; mf < 4; ++mf)
#pragma unroll
            for (int r = 0; r < 4; ++r)
                red[(mf * 16 + moff + r) * 68 + wn * 16 + lr] = acc[mf][r];
    }
    __syncthreads();
    if (kh == 1) {
        float* dst = part + (size_t)kseg * 64 * GG;
#pragma unroll
        for (int mf = 0; mf < 4; ++mf)
#pragma unroll
            for (int r = 0; r < 4; ++r) {
                int m = mf * 16 + moff + r;
                dst[(size_t)m * GG + n] = acc[mf][r] + red[m * 68 + wn * 16 + lr];
            }
    }
}

__global__ __launch_bounds__(256) void k_pw2(const float* __restrict__ part, int nseg,
                                             const float* __restrict__ bih,
                                             const float* __restrict__ bhh,
                                             u16* __restrict__ xh,
                                             u16* __restrict__ xl,
                                             float* __restrict__ c,
                                             float* __restrict__ out, int t) {
    int b = blockIdx.x;
    __shared__ float g[GG];
    __shared__ float cs1[NCHN], cs2[NCHN], t1[NCHN], t2[NCHN];
    int tid = threadIdx.x;
    for (int p = 0; p < 34; ++p) {
        int j = p * 256 + tid;
        float s = bih[j] + bhh[j];
        for (int ks = 0; ks < nseg; ++ks) s += part[(size_t)(ks * 64 + b) * GG + j];
        g[j] = s;
    }
    __syncthreads();
    float x1 = g[tid], x2 = g[NCHN + tid];
    t1[tid] = x1; t2[tid] = x2;
    __syncthreads();
    for (int s = 128; s > 0; s >>= 1) {
        if (tid < s) { t1[tid] = fmaxf(t1[tid], t1[tid + s]); t2[tid] = fmaxf(t2[tid], t2[tid + s]); }
        __syncthreads();
    }
    float m1 = t1[0], m2 = t2[0];
    __syncthreads();
    float e1 = __expf(x1 - m1), e2 = __expf(x2 - m2);
    t1[tid] = e1; t2[tid] = e2;
    __syncthreads();
    for (int s = 128; s > 0; s >>= 1) {
        if (tid < s) { t1[tid] += t1[tid + s]; t2[tid] += t2[tid + s]; }
        __syncthreads();
    }
    float inv1 = 1.f / t1[0], inv2 = 1.f / t2[0];
    __syncthreads();
    cs1[tid] = e1; cs2[tid] = e2;
    __syncthreads();
    for (int off = 1; off < NCHN; off <<= 1) {
        float a1 = (tid >= off) ? cs1[tid - off] : 0.f;
        float a2 = (tid >= off) ? cs2[tid - off] : 0.f;
        __syncthreads();
        cs1[tid] += a1; cs2[tid] += a2;
        __syncthreads();
    }
    float* cb = c + (size_t)b * DVV;
    float* ob = out + ((size_t)b * TDEC + t) * DVV;
    u16* xhb = xh + (size_t)b * KTOT + 1024;
    u16* xlb = xl + (size_t)b * KTOT + 1024;
    for (int p = 0; p < 8; ++p) {
        int idx = p * 256 + tid;
        int ch = idx >> 3;
        float cin = 1.f - cs1[ch] * inv1;
        float cfg = cs2[ch] * inv2;
        float ov = cfg * cin;
        float oo = sigmoid_fast(g[512 + idx]);
        float gg = tanh_fast(g[2560 + idx]);
        float ii = sigmoid_fast(g[4608 + idx]);
        float ff = sigmoid_fast(g[6656 + idx]);
        float fg = ff * ov + (cfg - ov);
        float ig = ii * ov + (cin - ov);
        float cy = fg * cb[idx] + ig * gg;
        cb[idx] = cy;
        float hy = oo * tanh_fast(cy);
        ob[idx] = hy;
        u16 hh = f2bf(hy);
        xhb[idx] = hh;
        xlb[idx] = f2bf(hy - bf2f(hh));
    }
}

// ===================== launch =====================

extern "C" void kernel_launch(void* const* d_in, const int* in_sizes, int n_in,
                              void* d_out, int out_size, void* d_ws, size_t ws_size,
                              hipStream_t stream) {
    const float* enc    = (const float*)d_in[0];
    const float* W_att1 = (const float*)d_in[2];
    const float* b_att1 = (const float*)d_in[3];
    const float* w_att2 = (const float*)d_in[4];
    const float* W_ih   = (const float*)d_in[5];
    const float* b_ih   = (const float*)d_in[6];
    const float* W_hh   = (const float*)d_in[7];
    const float* b_hh   = (const float*)d_in[8];
    float* out = (float*)d_out;
    float* ws  = (float*)d_ws;
    const float* Wh_att = W_att1 + 1024 * 1024;

    // layout (16B-aligned offsets)
    float* hWp  = ws;                          // 16*64*1024 = 1,048,576 f
    float* ebuf = hWp + 1048576;               // 8,192 f (fallback only)
    float* gp   = ebuf + 8192;                 // 8*64*8704 = 4,456,448 f
    float* c    = gp + 4456448;                // 131,072 f
    int*   bar  = (int*)(c + 131072);          // 8,448 ints
    u16* Pbf = (u16*)(bar + 8448);             // 8,388,608
    u16* xh  = Pbf + 8388608;                  // 196,608
    u16* xl  = xh + 196608;                    // 196,608
    u16* Wth = xl + 196608;                    // 26,738,688
    u16* Wtl = Wth + 26738688;                 // 26,738,688
    u16* Wta = Wtl + 26738688;                 // 2,097,152
    if (ws_size < 151323648ull) return;

    k_cvt<true><<<dim3(136, 48), 256, 0, stream>>>(W_ih, W_hh, 1024, GG, KTOT, Wth, Wtl);
    k_cvt<false><<<dim3(16, 32), 256, 0, stream>>>(Wh_att, Wh_att, 2048, DHH, 2048, Wta, Wta);
    k_Pb<<<dim3(16, 128), 256, 0, stream>>>(enc, W_att1, b_att1, Pbf);
    k_init2<<<768, 256, 0, stream>>>(c, xh, xl, bar);

    void* args[] = {(void*)&Pbf, (void*)&hWp, (void*)&gp, (void*)&c,
                    (void*)&xh, (void*)&xl, (void*)&Wth, (void*)&Wtl, (void*)&Wta,
                    (void*)&enc, (void*)&w_att2, (void*)&b_ih, (void*)&b_hh,
                    (void*)&out, (void*)&bar};
    hipError_t err = hipLaunchCooperativeKernel((const void*)k_decode,
                                                dim3(256), dim3(512), args, 0, stream);
    if (err != hipSuccess) {
        (void)hipGetLastError();
        for (int t = 0; t < TDEC; ++t) {
            k_mma1<<<dim3(16, 8), 512, 0, stream>>>(xh, Wta, hWp);
            k_e_bf<<<dim3(BB, 4), 256, 0, stream>>>(Pbf, hWp, w_att2, ebuf);
            k_sc2<<<dim3(BB, 4), 256, 0, stream>>>(ebuf, enc, xh, xl);
            k_mma3<4><<<dim3(136, 4), 512, 0, stream>>>(xh, xl, Wth, Wtl, gp);
            k_pw2<<<BB, 256, 0, stream>>>(gp, 4, b_ih, b_hh, xh, xl, c, out, t);
        }
    }
}